// Round 10
// baseline (243.921 us; speedup 1.0000x reference)
//
#include <hip/hip_runtime.h>
#include <stdint.h>

#define AS1 __attribute__((address_space(1)))
#define AS3 __attribute__((address_space(3)))

typedef __attribute__((ext_vector_type(8))) short bf16x8;   // 8 bf16 = 4 VGPRs
typedef __attribute__((ext_vector_type(4))) float f32x4;

#define NB 8
#define NT 1024
#define NE 1024
#define NH 16
#define BT (NB * NT)

__device__ __forceinline__ unsigned short f2bf(float f) {
    unsigned int u = __builtin_bit_cast(unsigned int, f);
    u += 0x7FFFu + ((u >> 16) & 1u);          // RNE
    return (unsigned short)(u >> 16);
}
// pack two f32 -> one u32 of 2 bf16 (RNE) in a single VALU op
__device__ __forceinline__ unsigned int cvt_pk_bf16(float lo, float hi) {
    unsigned int r;
    asm("v_cvt_pk_bf16_f32 %0, %1, %2" : "=v"(r) : "v"(lo), "v"(hi));
    return r;
}

// ---------------- fused f32 -> bf16 conversion, 7 segments ----------------
__global__ void k_cvt7(const float* __restrict__ hs, unsigned short* __restrict__ hsB,
                       const float* __restrict__ w1, unsigned short* __restrict__ w1B,
                       const float* __restrict__ w2, unsigned short* __restrict__ w2B,
                       const float* __restrict__ w3, unsigned short* __restrict__ w3B,
                       const float* __restrict__ w4, unsigned short* __restrict__ w4B,
                       const float* __restrict__ r1, unsigned short* __restrict__ r1B,
                       const float* __restrict__ r2, unsigned short* __restrict__ r2B)
{
    int blk = blockIdx.x;
    const float* s; unsigned short* d; int base;
    if      (blk < 8192)  { s = hs; d = hsB; base = 0; }
    else if (blk < 9216)  { s = w1; d = w1B; base = 8192; }
    else if (blk < 10240) { s = w2; d = w2B; base = 9216; }
    else if (blk < 11264) { s = w3; d = w3B; base = 10240; }
    else if (blk < 12288) { s = w4; d = w4B; base = 11264; }
    else if (blk < 16384) { s = r1; d = r1B; base = 12288; }
    else                  { s = r2; d = r2B; base = 16384; }
    int i = ((blk - base) * 256 + threadIdx.x) * 4;
    float4 f = *reinterpret_cast<const float4*>(s + i);
    ushort4 o;
    o.x = f2bf(f.x); o.y = f2bf(f.y); o.z = f2bf(f.z); o.w = f2bf(f.w);
    *reinterpret_cast<ushort4*>(d + i) = o;
}

// ====== 256x128 GEMM, BK=32, 3-buffer deep prefetch, 2 blocks/CU ==========
// 4 waves (2m x 2n), per-wave 128x64 out (same MM as before). LDS 72KB ->
// two co-resident blocks whose independent barrier groups overlap each
// other's LDS-drain/barrier stalls (m114). Stage t+2 while reading t;
// vmcnt(6) drains exactly tile t+1 per iteration. Chunk-XOR swizzle
// cb^( (row>>1)&3 ) both sides -> <=2-way bank aliasing (free).
struct GJob {
    const unsigned short* W;
    const float* bias;
    void* out;
    float scale;
    int routed;
};

template <bool OUT_F32>
__global__ __launch_bounds__(256, 2)
void k_gemmP(const unsigned short* __restrict__ A,
             GJob j0, GJob j1, GJob j2, GJob j3, GJob j4,
             const int* __restrict__ rt)
{
    __shared__ __attribute__((aligned(16))) unsigned short LA[3][256 * 32];  // 16KB x3
    __shared__ __attribute__((aligned(16))) unsigned short LBb[3][128 * 32]; // 8KB x3

    // decode: xcd-major; per XCD: 4 m-panels shared across all jobs
    const int flat = blockIdx.x;
    const int xcd = flat & 7;
    const int l   = flat >> 3;          // 0..159 (proj) / 0..31 (Wo)
    const int pz  = l >> 5;             // job
    const int r   = l & 31;
    const int by  = xcd * 4 + (r >> 3); // 0..31
    const int bx  = r & 7;              // 0..7
    const int m0 = by << 8, n0 = bx << 7;

    GJob jb = j0;
    if (pz == 1) jb = j1;
    else if (pz == 2) jb = j2;
    else if (pz == 3) jb = j3;
    else if (pz == 4) jb = j4;
    int g = jb.routed ? rt[m0 >> 10] : 0;
    const unsigned short* Wg = jb.W + (size_t)g * NE * NE;

    const int tid  = threadIdx.x;
    const int wid  = tid >> 6;
    const int lane = tid & 63;
    const int frow = lane & 15;
    const int g4   = lane >> 4;
    const int wm = wid >> 1, wn = wid & 1;

    const unsigned short* baseA = A  + (size_t)m0 * NE;
    const unsigned short* baseB = Wg + (size_t)n0 * NE;

    auto STAGE_A = [&](int buf, int kt) {
#pragma unroll
        for (int j = 0; j < 4; ++j) {
            int c = tid + j * 256;              // 0..1023
            int row = c >> 2, cb = c & 3;
            const unsigned short* src = baseA + (size_t)row * NE + kt * 32
                                        + ((cb ^ ((row >> 1) & 3)) * 8);
            __builtin_amdgcn_global_load_lds((AS1 void*)src,
                (AS3 void*)(&LA[buf][0] + c * 8), 16, 0, 0);
        }
    };
    auto STAGE_B = [&](int buf, int kt) {
#pragma unroll
        for (int j = 0; j < 2; ++j) {
            int c = tid + j * 256;              // 0..511
            int row = c >> 2, cb = c & 3;
            const unsigned short* src = baseB + (size_t)row * NE + kt * 32
                                        + ((cb ^ ((row >> 1) & 3)) * 8);
            __builtin_amdgcn_global_load_lds((AS1 void*)src,
                (AS3 void*)(&LBb[buf][0] + c * 8), 16, 0, 0);
        }
    };

    f32x4 acc[8][4];
#pragma unroll
    for (int m = 0; m < 8; ++m)
#pragma unroll
        for (int n = 0; n < 4; ++n) acc[m][n] = (f32x4){0.f, 0.f, 0.f, 0.f};

    bf16x8 a4[4], b4[4];
    auto RDA = [&](int buf, int mh) {
#pragma unroll
        for (int mf = 0; mf < 4; ++mf) {
            int row = wm * 128 + mh * 64 + mf * 16 + frow;
            a4[mf] = *reinterpret_cast<const bf16x8*>(
                &LA[buf][row * 32 + ((g4 ^ ((row >> 1) & 3)) * 8)]);
        }
    };
    auto RDB = [&](int buf) {
#pragma unroll
        for (int nf = 0; nf < 4; ++nf) {
            int row = wn * 64 + nf * 16 + frow;
            b4[nf] = *reinterpret_cast<const bf16x8*>(
                &LBb[buf][row * 32 + ((g4 ^ ((row >> 1) & 3)) * 8)]);
        }
    };
    auto MM = [&](int mh) {
        __builtin_amdgcn_s_setprio(1);
#pragma unroll
        for (int mf = 0; mf < 4; ++mf)
#pragma unroll
            for (int nf = 0; nf < 4; ++nf)
                acc[mh * 4 + mf][nf] =
                    __builtin_amdgcn_mfma_f32_16x16x32_bf16(a4[mf], b4[nf], acc[mh * 4 + mf][nf], 0, 0, 0);
        __builtin_amdgcn_s_setprio(0);
    };

#define BARX __builtin_amdgcn_s_barrier()
#define LGK0 asm volatile("s_waitcnt lgkmcnt(0)" ::: "memory")
#define VMC6 asm volatile("s_waitcnt vmcnt(6)" ::: "memory")
#define VMC0 asm volatile("s_waitcnt vmcnt(0)" ::: "memory")

    // prologue: tiles 0,1 into bufs 0,1; drain tile 0 (12 -> 6 outstanding)
    STAGE_A(0, 0); STAGE_B(0, 0); STAGE_A(1, 1); STAGE_B(1, 1);
    VMC6; BARX;

    int bt = 0;
#pragma unroll 1
    for (int t = 0; t < 32; ++t) {
        const int b2 = (bt + 2 >= 3) ? bt - 1 : bt + 2;   // (t+2)%3
        const bool pre = (t + 2 < 32);
        // ph0
        RDA(bt, 0); RDB(bt);
        if (pre) STAGE_A(b2, t + 2);
        BARX; LGK0; MM(0); BARX;
        // ph1
        RDA(bt, 1);
        if (pre) STAGE_B(b2, t + 2);
        BARX; LGK0; MM(1);
        if (t < 30) { VMC6; } else if (t == 30) { VMC0; }
        BARX;
        bt = (bt + 1 >= 3) ? 0 : bt + 1;
    }
#undef BARX
#undef LGK0
#undef VMC6
#undef VMC0

    const float* biasg = jb.bias + (size_t)g * NE;
#pragma unroll
    for (int am = 0; am < 8; ++am) {
        int row = m0 + wm * 128 + am * 16 + g4 * 4;
#pragma unroll
        for (int nf = 0; nf < 4; ++nf) {
            int col = n0 + wn * 64 + nf * 16 + frow;
            float bv = biasg[col];
            f32x4 v = acc[am][nf];
#pragma unroll
            for (int r2 = 0; r2 < 4; ++r2) {
                float val = (v[r2] + bv) * jb.scale;
                if (OUT_F32)
                    ((float*)jb.out)[(size_t)(row + r2) * NE + col] = val;
                else
                    ((unsigned short*)jb.out)[(size_t)(row + r2) * NE + col] = f2bf(val);
            }
        }
    }
}

// ---------------- V transpose: Vt[(b,h),d,s] = V[b,s,h*64+d] ----------------
__global__ void k_vtrans(const unsigned short* __restrict__ V, unsigned short* __restrict__ Vt) {
    __shared__ unsigned short tile[64][65];
    const int blk = blockIdx.x;
    const int bh = blk >> 4;
    const int b = bh >> 4;
    const int h = bh & 15;
    const int s0 = (blk & 15) * 64;
    const int tid = threadIdx.x;
#pragma unroll
    for (int i = 0; i < 2; ++i) {
        int seg = tid + i * 256;
        int row = seg >> 3;
        int c8 = (seg & 7) * 8;
        const unsigned short* src = V + (size_t)(b * NT + s0 + row) * NE + h * 64 + c8;
        ushort4 u0 = *reinterpret_cast<const ushort4*>(src);
        ushort4 u1 = *reinterpret_cast<const ushort4*>(src + 4);
        tile[row][c8 + 0] = u0.x; tile[row][c8 + 1] = u0.y;
        tile[row][c8 + 2] = u0.z; tile[row][c8 + 3] = u0.w;
        tile[row][c8 + 4] = u1.x; tile[row][c8 + 5] = u1.y;
        tile[row][c8 + 6] = u1.z; tile[row][c8 + 7] = u1.w;
    }
    __syncthreads();
#pragma unroll
    for (int i = 0; i < 2; ++i) {
        int seg = tid + i * 256;
        int drow = seg >> 3;
        int s8 = (seg & 7) * 8;
        ushort4 u0, u1;
        u0.x = tile[s8 + 0][drow]; u0.y = tile[s8 + 1][drow];
        u0.z = tile[s8 + 2][drow]; u0.w = tile[s8 + 3][drow];
        u1.x = tile[s8 + 4][drow]; u1.y = tile[s8 + 5][drow];
        u1.z = tile[s8 + 6][drow]; u1.w = tile[s8 + 7][drow];
        unsigned short* dst = Vt + (size_t)(bh * 64 + drow) * NT + s0 + s8;
        *reinterpret_cast<ushort4*>(dst) = u0;
        *reinterpret_cast<ushort4*>(dst + 4) = u1;
    }
}

// ---------------- fused dual-stream attention, swapped-QK^T ------------------
// (unchanged from R7)
__global__ __launch_bounds__(512, 4)
void k_attn(const unsigned short* __restrict__ Q,
            const unsigned short* __restrict__ K,
            const unsigned short* __restrict__ Qr,
            const unsigned short* __restrict__ Kr,
            const unsigned short* __restrict__ Vt,
            unsigned short* __restrict__ attnO)
{
    constexpr int PLD = 40;   // 80B rows (16B-aligned); half-tile = 16 rows x 32 s
    __shared__ __attribute__((aligned(16))) unsigned short KV[2][3 * 4096];   // Kg|Kr|V 8KB each
    __shared__ __attribute__((aligned(16))) unsigned short Pga[8][16 * PLD];  // per-wave Pg half
    __shared__ __attribute__((aligned(16))) unsigned short Pra[8][16 * PLD];  // per-wave Pr half

    const int blk = (blockIdx.x & 7) * 128 + (blockIdx.x >> 3);
    const int tile = blk & 7;
    const int bh = blk >> 3;
    const int b = bh >> 4;
    const int h = bh & 15;
    const int wid = threadIdx.x >> 6;
    const int lane = threadIdx.x & 63;
    const int frow = lane & 15;
    const int g4 = lane >> 4;
    const int f7 = frow & 7;
    const int fk8 = g4 * 8;
    const int t0 = tile * 128 + wid * 16;

    const size_t qoff = (size_t)(b * NT + t0 + frow) * NE + h * 64;
    const bf16x8 qf0 = *reinterpret_cast<const bf16x8*>(Q + qoff + fk8);
    const bf16x8 qf1 = *reinterpret_cast<const bf16x8*>(Q + qoff + 32 + fk8);
    const bf16x8 qr0 = *reinterpret_cast<const bf16x8*>(Qr + qoff + fk8);
    const bf16x8 qr1 = *reinterpret_cast<const bf16x8*>(Qr + qoff + 32 + fk8);

    const unsigned short* Kb  = K  + (size_t)b * NT * NE + h * 64;
    const unsigned short* Krb = Kr + (size_t)b * NT * NE + h * 64;
    const unsigned short* Vtb = Vt + (size_t)bh * 64 * NT;
    unsigned short* PgRow = &Pga[wid][0] + frow * PLD;
    unsigned short* PrRow = &Pra[wid][0] + frow * PLD;

    f32x4 og[4], orr[4];
    float lgp = 0.f, lrp = 0.f;
#pragma unroll
    for (int i = 0; i < 4; ++i) {
        og[i] = (f32x4){0.f, 0.f, 0.f, 0.f};
        orr[i] = (f32x4){0.f, 0.f, 0.f, 0.f};
    }

    const int srow = threadIdx.x >> 3;                         // 0..63
    const int scb8 = ((threadIdx.x & 7) ^ (srow & 7)) * 8;
    auto stage = [&](int buf, int s0) {
        const unsigned short* sK = Kb  + (size_t)(s0 + srow) * NE + scb8;
        const unsigned short* sR = Krb + (size_t)(s0 + srow) * NE + scb8;
        const unsigned short* sV = Vtb + (size_t)srow * NT + s0 + scb8;
        __builtin_amdgcn_global_load_lds((AS1 void*)sK, (AS3 void*)(&KV[buf][wid * 512]), 16, 0, 0);
        __builtin_amdgcn_global_load_lds((AS1 void*)sR, (AS3 void*)(&KV[buf][4096 + wid * 512]), 16, 0, 0);
        __builtin_amdgcn_global_load_lds((AS1 void*)sV, (AS3 void*)(&KV[buf][8192 + wid * 512]), 16, 0, 0);
    };

    stage(0, 0);
    __syncthreads();
    int cur = 0;
    const f32x4 z = (f32x4){0.f, 0.f, 0.f, 0.f};
#pragma unroll 1
    for (int t = 0; t < NT / 64; ++t) {
        if (t < NT / 64 - 1) stage(cur ^ 1, (t + 1) * 64);
        const unsigned short* Kl  = &KV[cur][0];
        const unsigned short* Krl = &KV[cur][4096];
        const unsigned short* Vl  = &KV[cur][8192];

        // QK^T swapped: sg[nf] lane = S[q=frow][s=16nf+4g4+r]
        f32x4 sg[4], sr[4];
#pragma unroll
        for (int nf = 0; nf < 4; ++nf) {
            const int ro = (nf * 16 + frow) * 64;
            bf16x8 kA = *reinterpret_cast<const bf16x8*>(Kl + ro + ((g4 ^ f7) * 8));
            bf16x8 kB = *reinterpret_cast<const bf16x8*>(Kl + ro + (((4 + g4) ^ f7) * 8));
            bf16x8 rA = *reinterpret_cast<const bf16x8*>(Krl + ro + ((g4 ^ f7) * 8));
            bf16x8 rB = *reinterpret_cast<const bf16x8*>(Krl + ro + (((4 + g4) ^ f7) * 8));
            sg[nf] = __builtin_amdgcn_mfma_f32_16x16x32_bf16(kA, qf0, z, 0, 0, 0);
            sg[nf] = __builtin_amdgcn_mfma_f32_16x16x32_bf16(kB, qf1, sg[nf], 0, 0, 0);
            sr[nf] = __builtin_amdgcn_mfma_f32_16x16x32_bf16(rA, qr0, z, 0, 0, 0);
            sr[nf] = __builtin_amdgcn_mfma_f32_16x16x32_bf16(rB, qr1, sr[nf], 0, 0, 0);
        }

        // two s-halves: pack both streams, one wait, PV with shared V-frags
#pragma unroll
        for (int hh = 0; hh < 2; ++hh) {
#pragma unroll
            for (int j = 0; j < 2; ++j) {
                const int nf = 2 * hh + j;
                float g0 = __expf(sg[nf][0]), g1 = __expf(sg[nf][1]);
                float g2 = __expf(sg[nf][2]), g3 = __expf(sg[nf][3]);
                lgp += (g0 + g1) + (g2 + g3);
                uint2 wg;
                wg.x = cvt_pk_bf16(g0, g1);
                wg.y = cvt_pk_bf16(g2, g3);
                *reinterpret_cast<uint2*>(PgRow + j * 16 + g4 * 4) = wg;
                float r0 = __expf(sr[nf][0]), r1 = __expf(sr[nf][1]);
                float r2 = __expf(sr[nf][2]), r3 = __expf(sr[nf][3]);
                lrp += (r0 + r1) + (r2 + r3);
                uint2 wr;
                wr.x = cvt_pk_bf16(r0, r1);
                wr.y = cvt_pk_bf16(r2, r3);
                *reinterpret_cast<uint2*>(PrRow + j * 16 + g4 * 4) = wr;
            }
            asm volatile("s_waitcnt lgkmcnt(0)" ::: "memory");   // P visible (same wave)
            bf16x8 pg = *reinterpret_cast<const bf16x8*>(PgRow + fk8);
            bf16x8 pr = *reinterpret_cast<const bf16x8*>(PrRow + fk8);
            __builtin_amdgcn_s_setprio(1);
#pragma unroll
            for (int nf2 = 0; nf2 < 4; ++nf2) {
                const int vo = (nf2 * 16 + frow) * 64;
                bf16x8 v = *reinterpret_cast<const bf16x8*>(Vl + vo + (((4 * hh + g4) ^ f7) * 8));
                og[nf2]  = __builtin_amdgcn_mfma_f32_16x16x32_bf16(pg, v, og[nf2], 0, 0, 0);
                orr[nf2] = __builtin_amdgcn_mfma_f32_16x16x32_bf16(pr, v, orr[nf2], 0, 0, 0);
            }
            __builtin_amdgcn_s_setprio(0);
        }

        __syncthreads();   // drains vmcnt (next KV tile staged) + overwrite fence
        cur ^= 1;
    }

    // full row sums for q-row frow (reduce across the 4 g4 lanes)
    lgp += __shfl_xor(lgp, 16); lgp += __shfl_xor(lgp, 32);
    lrp += __shfl_xor(lrp, 16); lrp += __shfl_xor(lrp, 32);
    float ig = 0.45f / lgp, ir = 0.05f / lrp;
    float igr[4], irr[4];
#pragma unroll
    for (int r = 0; r < 4; ++r) {
        igr[r] = __shfl(ig, g4 * 4 + r);
        irr[r] = __shfl(ir, g4 * 4 + r);
    }
#pragma unroll
    for (int nf2 = 0; nf2 < 4; ++nf2) {
#pragma unroll
        for (int r = 0; r < 4; ++r) {
            float val = og[nf2][r] * igr[r] + orr[nf2][r] * irr[r];
            int tq = t0 + g4 * 4 + r;
            attnO[(size_t)(b * NT + tq) * NE + h * 64 + nf2 * 16 + frow] = f2bf(val);
        }
    }
}

// ---------------- launcher ----------------
extern "C" void kernel_launch(void* const* d_in, const int* in_sizes, int n_in,
                              void* d_out, int out_size, void* d_ws, size_t ws_size,
                              hipStream_t stream)
{
    const float* hs  = (const float*)d_in[0];
    const int*   rt  = (const int*)d_in[1];
    const float* Wq  = (const float*)d_in[2];
    const float* bq  = (const float*)d_in[3];
    const float* Wk  = (const float*)d_in[4];
    const float* bk  = (const float*)d_in[5];
    const float* Wv  = (const float*)d_in[6];
    const float* bv  = (const float*)d_in[7];
    const float* Wo  = (const float*)d_in[8];
    const float* bo  = (const float*)d_in[9];
    const float* RWq = (const float*)d_in[10];
    const float* Rbq = (const float*)d_in[11];
    const float* RWk = (const float*)d_in[12];
    const float* Rbk = (const float*)d_in[13];

    unsigned short* w = (unsigned short*)d_ws;
    const size_t NBT = (size_t)BT * NE;   // 8M elems
    const size_t NW  = (size_t)NE * NE;   // 1M elems
    unsigned short* hsB  = w; w += NBT;
    unsigned short* Qb   = w; w += NBT;
    unsigned short* Kb   = w; w += NBT;
    unsigned short* Vb   = w; w += NBT;
    unsigned short* Qrb  = w; w += NBT;
    unsigned short* Krb  = w; w += NBT;
    unsigned short* Vtb  = w; w += NBT;
    unsigned short* atb  = w; w += NBT;
    unsigned short* WqB  = w; w += NW;
    unsigned short* WkB  = w; w += NW;
    unsigned short* WvB  = w; w += NW;
    unsigned short* WoB  = w; w += NW;
    unsigned short* RWqB = w; w += 4 * NW;
    unsigned short* RWkB = w; w += 4 * NW;

    k_cvt7<<<dim3(20480), dim3(256), 0, stream>>>(hs, hsB, Wq, WqB, Wk, WkB, Wv, WvB,
                                                  Wo, WoB, RWq, RWqB, RWk, RWkB);

    GJob jq  = { WqB,  bq,  Qb,  0.125f, 0 };
    GJob jk  = { WkB,  bk,  Kb,  1.0f,   0 };
    GJob jv  = { WvB,  bv,  Vb,  1.0f,   0 };
    GJob jrq = { RWqB, Rbq, Qrb, 0.125f, 1 };
    GJob jrk = { RWkB, Rbk, Krb, 1.0f,   1 };
    k_gemmP<false><<<dim3(1280), dim3(256), 0, stream>>>(hsB, jq, jk, jv, jrq, jrk, rt);

    k_vtrans<<<dim3(NB * NH * 16), dim3(256), 0, stream>>>(Vb, Vtb);
    k_attn<<<dim3(NB * NH * 8), dim3(512), 0, stream>>>(Qb, Kb, Qrb, Krb, Vtb, atb);

    GJob jo = { WoB, bo, d_out, 1.0f, 0 };
    k_gemmP<true><<<dim3(256), dim3(256), 0, stream>>>(atb, jo, jo, jo, jo, jo, nullptr);
}

// Round 11
// 242.719 us; speedup vs baseline: 1.0050x; 1.0050x over previous
//
#include <hip/hip_runtime.h>
#include <stdint.h>

#define AS1 __attribute__((address_space(1)))
#define AS3 __attribute__((address_space(3)))

typedef __attribute__((ext_vector_type(8))) short bf16x8;   // 8 bf16 = 4 VGPRs
typedef __attribute__((ext_vector_type(4))) float f32x4;

#define NB 8
#define NT 1024
#define NE 1024
#define NH 16
#define BT (NB * NT)

__device__ __forceinline__ unsigned short f2bf(float f) {
    unsigned int u = __builtin_bit_cast(unsigned int, f);
    u += 0x7FFFu + ((u >> 16) & 1u);          // RNE
    return (unsigned short)(u >> 16);
}
// pack two f32 -> one u32 of 2 bf16 (RNE) in a single VALU op
__device__ __forceinline__ unsigned int cvt_pk_bf16(float lo, float hi) {
    unsigned int r;
    asm("v_cvt_pk_bf16_f32 %0, %1, %2" : "=v"(r) : "v"(lo), "v"(hi));
    return r;
}

// ---------------- fused f32 -> bf16 conversion, 7 segments ----------------
__global__ void k_cvt7(const float* __restrict__ hs, unsigned short* __restrict__ hsB,
                       const float* __restrict__ w1, unsigned short* __restrict__ w1B,
                       const float* __restrict__ w2, unsigned short* __restrict__ w2B,
                       const float* __restrict__ w3, unsigned short* __restrict__ w3B,
                       const float* __restrict__ w4, unsigned short* __restrict__ w4B,
                       const float* __restrict__ r1, unsigned short* __restrict__ r1B,
                       const float* __restrict__ r2, unsigned short* __restrict__ r2B)
{
    int blk = blockIdx.x;
    const float* s; unsigned short* d; int base;
    if      (blk < 8192)  { s = hs; d = hsB; base = 0; }
    else if (blk < 9216)  { s = w1; d = w1B; base = 8192; }
    else if (blk < 10240) { s = w2; d = w2B; base = 9216; }
    else if (blk < 11264) { s = w3; d = w3B; base = 10240; }
    else if (blk < 12288) { s = w4; d = w4B; base = 11264; }
    else if (blk < 16384) { s = r1; d = r1B; base = 12288; }
    else                  { s = r2; d = r2B; base = 16384; }
    int i = ((blk - base) * 256 + threadIdx.x) * 4;
    float4 f = *reinterpret_cast<const float4*>(s + i);
    ushort4 o;
    o.x = f2bf(f.x); o.y = f2bf(f.y); o.z = f2bf(f.z); o.w = f2bf(f.w);
    *reinterpret_cast<ushort4*>(d + i) = o;
}

// ============ 256x256 8-phase GEMM (reverted to R8 best-measured) ==========
struct GJob {
    const unsigned short* W;
    const float* bias;
    void* out;
    float scale;
    int routed;
};

template <bool OUT_F32>
__global__ __launch_bounds__(512, 2)
void k_gemm256(const unsigned short* __restrict__ A,
               GJob j0, GJob j1, GJob j2, GJob j3, GJob j4,
               const int* __restrict__ rt)
{
    __shared__ __attribute__((aligned(16))) unsigned short LB[2][2][2][128 * 64];

    const int flat = blockIdx.x;
    const int xcd = flat & 7;           // consecutive blocks round-robin XCDs
    const int l   = flat >> 3;          // sequence within this XCD
    const int pz  = l >> 4;             // job
    const int r   = l & 15;
    const int by  = xcd * 4 + (r >> 2); // 4 m-panels per XCD, all jobs
    const int bx  = r & 3;
    const int m0 = by << 8, n0 = bx << 8;

    GJob jb = j0;
    if (pz == 1) jb = j1;
    else if (pz == 2) jb = j2;
    else if (pz == 3) jb = j3;
    else if (pz == 4) jb = j4;
    int g = jb.routed ? rt[m0 >> 10] : 0;
    const unsigned short* Wg = jb.W + (size_t)g * NE * NE;

    const int tid  = threadIdx.x;
    const int wid  = tid >> 6;
    const int lane = tid & 63;
    const int frow = lane & 15;
    const int g4   = lane >> 4;
    const int wm = wid >> 2, wn = wid & 3;

    const int rh0  = tid >> 3;
    const int swz8 = ((tid & 7) ^ (rh0 & 7)) * 8;
    const unsigned short* baseA = A  + (size_t)m0 * NE;
    const unsigned short* baseB = Wg + (size_t)n0 * NE;

    auto STAGE = [&](int d, int mat, int half, int kt) {
        const unsigned short* base = mat ? baseB : baseA;
#pragma unroll
        for (int j = 0; j < 2; ++j) {
            const unsigned short* src =
                base + (size_t)(half * 128 + rh0 + j * 64) * NE + kt * 64 + swz8;
            __builtin_amdgcn_global_load_lds((AS1 void*)src,
                (AS3 void*)&LB[d][mat][half][(wid * 64 + j * 512) * 8], 16, 0, 0);
        }
    };

    f32x4 acc[8][4];
#pragma unroll
    for (int m = 0; m < 8; ++m)
#pragma unroll
        for (int n = 0; n < 4; ++n) acc[m][n] = (f32x4){0.f, 0.f, 0.f, 0.f};

    bf16x8 a4[4], b4[4];
    auto RDA = [&](int d, int mh, int kh) {
#pragma unroll
        for (int mf = 0; mf < 4; ++mf) {
            int rh = mh * 64 + mf * 16 + frow;
            int off = rh * 64 + (((kh * 4 + g4) ^ (frow & 7)) * 8);
            a4[mf] = *reinterpret_cast<const bf16x8*>(&LB[d][0][wm][off]);
        }
    };
    auto RDB = [&](int d, int kh) {
#pragma unroll
        for (int nf = 0; nf < 4; ++nf) {
            int rh = (wn & 1) * 64 + nf * 16 + frow;
            int off = rh * 64 + (((kh * 4 + g4) ^ (frow & 7)) * 8);
            b4[nf] = *reinterpret_cast<const bf16x8*>(&LB[d][1][wn >> 1][off]);
        }
    };
    auto MM = [&](int mh) {
        __builtin_amdgcn_s_setprio(1);
#pragma unroll
        for (int mf = 0; mf < 4; ++mf)
#pragma unroll
            for (int nf = 0; nf < 4; ++nf)
                acc[mh * 4 + mf][nf] =
                    __builtin_amdgcn_mfma_f32_16x16x32_bf16(a4[mf], b4[nf], acc[mh * 4 + mf][nf], 0, 0, 0);
        __builtin_amdgcn_s_setprio(0);
    };

#define BARX __builtin_amdgcn_s_barrier()
#define LGK0 asm volatile("s_waitcnt lgkmcnt(0)" ::: "memory")
#define VMC2 asm volatile("s_waitcnt vmcnt(2)" ::: "memory")

    STAGE(0, 0, 0, 0); STAGE(0, 0, 1, 0); STAGE(0, 1, 0, 0); STAGE(0, 1, 1, 0);
    STAGE(1, 1, 0, 1);
    VMC2; BARX;

#pragma unroll 1
    for (int i = 0; i < 8; ++i) {
        const int t = 2 * i;
        const bool pre = (i < 7);
        RDA(0, 0, 0); RDB(0, 0); STAGE(1, 1, 1, t + 1);
        BARX; LGK0; MM(0); BARX;
        RDA(0, 1, 0); STAGE(1, 0, 0, t + 1);
        BARX; LGK0; MM(1); BARX;
        RDA(0, 0, 1); RDB(0, 1); STAGE(1, 0, 1, t + 1);
        BARX; LGK0; MM(0); BARX;
        RDA(0, 1, 1); if (pre) STAGE(0, 1, 0, t + 2);
        BARX; LGK0; MM(1); VMC2; BARX;
        RDA(1, 0, 0); RDB(1, 0); if (pre) STAGE(0, 1, 1, t + 2);
        BARX; LGK0; MM(0); BARX;
        RDA(1, 1, 0); if (pre) STAGE(0, 0, 0, t + 2);
        BARX; LGK0; MM(1); BARX;
        RDA(1, 0, 1); RDB(1, 1); if (pre) STAGE(0, 0, 1, t + 2);
        BARX; LGK0; MM(0); BARX;
        RDA(1, 1, 1); if (pre) STAGE(1, 1, 0, t + 3);
        BARX; LGK0; MM(1); VMC2; BARX;
    }
#undef BARX
#undef LGK0
#undef VMC2

    const float* biasg = jb.bias + (size_t)(jb.routed ? (rt[m0 >> 10]) : 0) * NE;
#pragma unroll
    for (int am = 0; am < 8; ++am) {
        int row = m0 + wm * 128 + am * 16 + g4 * 4;
#pragma unroll
        for (int nf = 0; nf < 4; ++nf) {
            int col = n0 + wn * 64 + nf * 16 + frow;
            float bv = biasg[col];
            f32x4 v = acc[am][nf];
#pragma unroll
            for (int r2 = 0; r2 < 4; ++r2) {
                float val = (v[r2] + bv) * jb.scale;
                if (OUT_F32)
                    ((float*)jb.out)[(size_t)(row + r2) * NE + col] = val;
                else
                    ((unsigned short*)jb.out)[(size_t)(row + r2) * NE + col] = f2bf(val);
            }
        }
    }
}

// ---------------- V transpose: Vt[(b,h),d,s] = V[b,s,h*64+d] ----------------
__global__ void k_vtrans(const unsigned short* __restrict__ V, unsigned short* __restrict__ Vt) {
    __shared__ unsigned short tile[64][65];
    const int blk = blockIdx.x;
    const int bh = blk >> 4;
    const int b = bh >> 4;
    const int h = bh & 15;
    const int s0 = (blk & 15) * 64;
    const int tid = threadIdx.x;
#pragma unroll
    for (int i = 0; i < 2; ++i) {
        int seg = tid + i * 256;
        int row = seg >> 3;
        int c8 = (seg & 7) * 8;
        const unsigned short* src = V + (size_t)(b * NT + s0 + row) * NE + h * 64 + c8;
        ushort4 u0 = *reinterpret_cast<const ushort4*>(src);
        ushort4 u1 = *reinterpret_cast<const ushort4*>(src + 4);
        tile[row][c8 + 0] = u0.x; tile[row][c8 + 1] = u0.y;
        tile[row][c8 + 2] = u0.z; tile[row][c8 + 3] = u0.w;
        tile[row][c8 + 4] = u1.x; tile[row][c8 + 5] = u1.y;
        tile[row][c8 + 6] = u1.z; tile[row][c8 + 7] = u1.w;
    }
    __syncthreads();
#pragma unroll
    for (int i = 0; i < 2; ++i) {
        int seg = tid + i * 256;
        int drow = seg >> 3;
        int s8 = (seg & 7) * 8;
        ushort4 u0, u1;
        u0.x = tile[s8 + 0][drow]; u0.y = tile[s8 + 1][drow];
        u0.z = tile[s8 + 2][drow]; u0.w = tile[s8 + 3][drow];
        u1.x = tile[s8 + 4][drow]; u1.y = tile[s8 + 5][drow];
        u1.z = tile[s8 + 6][drow]; u1.w = tile[s8 + 7][drow];
        unsigned short* dst = Vt + (size_t)(bh * 64 + drow) * NT + s0 + s8;
        *reinterpret_cast<ushort4*>(dst) = u0;
        *reinterpret_cast<ushort4*>(dst + 4) = u1;
    }
}

// -------- fused dual-stream attention, 32 q-rows/wave (4-wave blocks) -------
// Each K/Kr-frag read feeds 2 MFMAs (two q-halves), V-frags feed 4 (2 streams
// x 2 qh): LDS bytes/MFMA 1.0 -> 0.625 KB. Grid 1024 (8 blocks/head), 2
// blocks/CU (58KB LDS, VGPR<=256 via launch_bounds(256,2)). Stream-serial
// per-wave P buffer (DS in-order per wave). No-max exp accumulation.
__global__ __launch_bounds__(256, 2)
void k_attn(const unsigned short* __restrict__ Q,
            const unsigned short* __restrict__ K,
            const unsigned short* __restrict__ Qr,
            const unsigned short* __restrict__ Kr,
            const unsigned short* __restrict__ Vt,
            unsigned short* __restrict__ attnO)
{
    constexpr int PLD = 40;   // 80B rows; P half-tile = 32 q-rows x 32 s
    __shared__ __attribute__((aligned(16))) unsigned short KV[2][3 * 4096];  // 48KB
    __shared__ __attribute__((aligned(16))) unsigned short Ps[4][32 * PLD];  // 10KB

    // bijective XCD swizzle: all 8 blocks of one head on one XCD
    const int blk = (blockIdx.x & 7) * 128 + (blockIdx.x >> 3);
    const int tile = blk & 7;
    const int bh = blk >> 3;
    const int b = bh >> 4;
    const int h = bh & 15;
    const int tid = threadIdx.x;
    const int wid = tid >> 6;          // 0..3
    const int lane = tid & 63;
    const int frow = lane & 15;
    const int g4 = lane >> 4;
    const int f7 = frow & 7;
    const int fk8 = g4 * 8;
    const int t0 = tile * 128 + wid * 32;

    // Q frags [qh][kh]
    bf16x8 qf[2][2], qr[2][2];
#pragma unroll
    for (int qh = 0; qh < 2; ++qh) {
        const size_t qoff = (size_t)(b * NT + t0 + qh * 16 + frow) * NE + h * 64;
        qf[qh][0] = *reinterpret_cast<const bf16x8*>(Q + qoff + fk8);
        qf[qh][1] = *reinterpret_cast<const bf16x8*>(Q + qoff + 32 + fk8);
        qr[qh][0] = *reinterpret_cast<const bf16x8*>(Qr + qoff + fk8);
        qr[qh][1] = *reinterpret_cast<const bf16x8*>(Qr + qoff + 32 + fk8);
    }

    const unsigned short* Kb  = K  + (size_t)b * NT * NE + h * 64;
    const unsigned short* Krb = Kr + (size_t)b * NT * NE + h * 64;
    const unsigned short* Vtb = Vt + (size_t)bh * 64 * NT;
    unsigned short* Pw = &Ps[wid][0];

    f32x4 og[2][4], orr[2][4];
    float lgp[2] = {0.f, 0.f}, lrp[2] = {0.f, 0.f};
#pragma unroll
    for (int qh = 0; qh < 2; ++qh)
#pragma unroll
        for (int i = 0; i < 4; ++i) {
            og[qh][i] = (f32x4){0.f, 0.f, 0.f, 0.f};
            orr[qh][i] = (f32x4){0.f, 0.f, 0.f, 0.f};
        }

    // staging: 64 rows x 8 chunks per 8KB section; 256 threads x 2 chunks.
    // chunk (row,cb) holds src[row][8*(cb ^ (row&7)) ..+8]; LDS dest linear.
    auto stage = [&](int buf, int s0) {
#pragma unroll
        for (int j = 0; j < 2; ++j) {
            int c = tid + j * 256;
            int row = c >> 3, cb = c & 7;
            int off = (cb ^ (row & 7)) * 8;
            const unsigned short* sK = Kb  + (size_t)(s0 + row) * NE + off;
            const unsigned short* sR = Krb + (size_t)(s0 + row) * NE + off;
            const unsigned short* sV = Vtb + (size_t)row * NT + s0 + off;
            const int dst = (wid * 64 + j * 256) * 8;
            __builtin_amdgcn_global_load_lds((AS1 void*)sK, (AS3 void*)(&KV[buf][dst]), 16, 0, 0);
            __builtin_amdgcn_global_load_lds((AS1 void*)sR, (AS3 void*)(&KV[buf][4096 + dst]), 16, 0, 0);
            __builtin_amdgcn_global_load_lds((AS1 void*)sV, (AS3 void*)(&KV[buf][8192 + dst]), 16, 0, 0);
        }
    };

    stage(0, 0);
    __syncthreads();
    int cur = 0;
    const f32x4 z = (f32x4){0.f, 0.f, 0.f, 0.f};
#pragma unroll 1
    for (int t = 0; t < NT / 64; ++t) {
        if (t < NT / 64 - 1) stage(cur ^ 1, (t + 1) * 64);
        const unsigned short* Kl  = &KV[cur][0];
        const unsigned short* Krl = &KV[cur][4096];
        const unsigned short* Vl  = &KV[cur][8192];

        // swapped QK^T: sg[qh][nf] lane = S[s=16nf+4g4+r][q=qh*16+frow]
        f32x4 sg[2][4], sr[2][4];
#pragma unroll
        for (int nf = 0; nf < 4; ++nf) {
            const int ro = (nf * 16 + frow) * 64;
            bf16x8 kA = *reinterpret_cast<const bf16x8*>(Kl + ro + ((g4 ^ f7) * 8));
            bf16x8 kB = *reinterpret_cast<const bf16x8*>(Kl + ro + (((4 + g4) ^ f7) * 8));
            bf16x8 rA = *reinterpret_cast<const bf16x8*>(Krl + ro + ((g4 ^ f7) * 8));
            bf16x8 rB = *reinterpret_cast<const bf16x8*>(Krl + ro + (((4 + g4) ^ f7) * 8));
#pragma unroll
            for (int qh = 0; qh < 2; ++qh) {
                sg[qh][nf] = __builtin_amdgcn_mfma_f32_16x16x32_bf16(kA, qf[qh][0], z, 0, 0, 0);
                sg[qh][nf] = __builtin_amdgcn_mfma_f32_16x16x32_bf16(kB, qf[qh][1], sg[qh][nf], 0, 0, 0);
                sr[qh][nf] = __builtin_amdgcn_mfma_f32_16x16x32_bf16(rA, qr[qh][0], z, 0, 0, 0);
                sr[qh][nf] = __builtin_amdgcn_mfma_f32_16x16x32_bf16(rB, qr[qh][1], sr[qh][nf], 0, 0, 0);
            }
        }

        // two s-halves; per half: pack-g, PV-g, pack-r, PV-r (V-frags shared)
#pragma unroll
        for (int hh = 0; hh < 2; ++hh) {
            bf16x8 v4[4];
#pragma unroll
            for (int nf2 = 0; nf2 < 4; ++nf2)
                v4[nf2] = *reinterpret_cast<const bf16x8*>(
                    Vl + (nf2 * 16 + frow) * 64 + (((4 * hh + g4) ^ f7) * 8));

#pragma unroll
            for (int qh = 0; qh < 2; ++qh) {
                unsigned short* Prow = Pw + (qh * 16 + frow) * PLD;
#pragma unroll
                for (int j = 0; j < 2; ++j) {
                    const int nf = 2 * hh + j;
                    float p0 = __expf(sg[qh][nf][0]), p1 = __expf(sg[qh][nf][1]);
                    float p2 = __expf(sg[qh][nf][2]), p3 = __expf(sg[qh][nf][3]);
                    lgp[qh] += (p0 + p1) + (p2 + p3);
                    uint2 wv;
                    wv.x = cvt_pk_bf16(p0, p1);
                    wv.y = cvt_pk_bf16(p2, p3);
                    *reinterpret_cast<uint2*>(Prow + j * 16 + g4 * 4) = wv;
                }
            }
            asm volatile("s_waitcnt lgkmcnt(0)" ::: "memory");   // P visible (same wave)
            {
                bf16x8 pg0 = *reinterpret_cast<const bf16x8*>(Pw + frow * PLD + fk8);
                bf16x8 pg1 = *reinterpret_cast<const bf16x8*>(Pw + (16 + frow) * PLD + fk8);
                __builtin_amdgcn_s_setprio(1);
#pragma unroll
                for (int nf2 = 0; nf2 < 4; ++nf2) {
                    og[0][nf2] = __builtin_amdgcn_mfma_f32_16x16x32_bf16(pg0, v4[nf2], og[0][nf2], 0, 0, 0);
                    og[1][nf2] = __builtin_amdgcn_mfma_f32_16x16x32_bf16(pg1, v4[nf2], og[1][nf2], 0, 0, 0);
                }
                __builtin_amdgcn_s_setprio(0);
            }
            // reader stream reuses P (DS pipe in-order per wave -> WAR safe)
#pragma unroll
            for (int qh = 0; qh < 2; ++qh) {
                unsigned short* Prow = Pw + (qh * 16 + frow) * PLD;
#pragma unroll
                for (int j = 0; j < 2; ++j) {
                    const int nf = 2 * hh + j;
                    float p0 = __expf(sr[qh][nf][0]), p1 = __expf(sr[qh][nf][1]);
                    float p2 = __expf(sr[qh][nf][2]), p3 = __expf(sr[qh][nf][3]);
                    lrp[qh] += (p0 + p1) + (p2 + p3);
                    uint2 wv;
                    wv.x = cvt_pk_bf16(p0, p1);
                    wv.y = cvt_pk_bf16(p2, p3);
                    *reinterpret_cast<uint2*>(Prow + j * 16 + g4 * 4) = wv;
                }
            }
            asm volatile("s_waitcnt lgkmcnt(0)" ::: "memory");
            {
                bf16x8 pr0 = *reinterpret_cast<const bf16x8*>(Pw + frow * PLD + fk8);
                bf16x8 pr1 = *reinterpret_cast<const bf16x8*>(Pw + (16 + frow) * PLD + fk8);
                __builtin_amdgcn_s_setprio(1);
#pragma unroll
                for (int nf2 = 0; nf2 < 4; ++nf2) {
                    orr[0][nf2] = __builtin_amdgcn_mfma_f32_16x16x32_bf16(pr0, v4[nf2], orr[0][nf2], 0, 0, 0);
                    orr[1][nf2] = __builtin_amdgcn_mfma_f32_16x16x32_bf16(pr1, v4[nf2], orr[1][nf2], 0, 0, 0);
                }
                __builtin_amdgcn_s_setprio(0);
            }
        }

        __syncthreads();   // drains vmcnt (next KV tile staged) + overwrite fence
        cur ^= 1;
    }

    // row sums (reduce over the 4 g4 lanes) + output
#pragma unroll
    for (int qh = 0; qh < 2; ++qh) {
        lgp[qh] += __shfl_xor(lgp[qh], 16); lgp[qh] += __shfl_xor(lgp[qh], 32);
        lrp[qh] += __shfl_xor(lrp[qh], 16); lrp[qh] += __shfl_xor(lrp[qh], 32);
        float ig = 0.45f / lgp[qh], ir = 0.05f / lrp[qh];
        float igr[4], irr[4];
#pragma unroll
        for (int r = 0; r < 4; ++r) {
            igr[r] = __shfl(ig, g4 * 4 + r);
            irr[r] = __shfl(ir, g4 * 4 + r);
        }
#pragma unroll
        for (int nf2 = 0; nf2 < 4; ++nf2) {
#pragma unroll
            for (int r = 0; r < 4; ++r) {
                float val = og[qh][nf2][r] * igr[r] + orr[qh][nf2][r] * irr[r];
                int tq = t0 + qh * 16 + g4 * 4 + r;
                attnO[(size_t)(b * NT + tq) * NE + h * 64 + nf2 * 16 + frow] = f2bf(val);
            }
        }
    }
}

// ---------------- launcher ----------------
extern "C" void kernel_launch(void* const* d_in, const int* in_sizes, int n_in,
                              void* d_out, int out_size, void* d_ws, size_t ws_size,
                              hipStream_t stream)
{
    const float* hs  = (const float*)d_in[0];
    const int*   rt  = (const int*)d_in[1];
    const float* Wq  = (const float*)d_in[2];
    const float* bq  = (const float*)d_in[3];
    const float* Wk  = (const float*)d_in[4];
    const float* bk  = (const float*)d_in[5];
    const float* Wv  = (const float*)d_in[6];
    const float* bv  = (const float*)d_in[7];
    const float* Wo  = (const float*)d_in[8];
    const float* bo  = (const float*)d_in[9];
    const float* RWq = (const float*)d_in[10];
    const float* Rbq = (const float*)d_in[11];
    const float* RWk = (const float*)d_in[12];
    const float* Rbk = (const float*)d_in[13];

    unsigned short* w = (unsigned short*)d_ws;
    const size_t NBT = (size_t)BT * NE;   // 8M elems
    const size_t NW  = (size_t)NE * NE;   // 1M elems
    unsigned short* hsB  = w; w += NBT;
    unsigned short* Qb   = w; w += NBT;
    unsigned short* Kb   = w; w += NBT;
    unsigned short* Vb   = w; w += NBT;
    unsigned short* Qrb  = w; w += NBT;
    unsigned short* Krb  = w; w += NBT;
    unsigned short* Vtb  = w; w += NBT;
    unsigned short* atb  = w; w += NBT;
    unsigned short* WqB  = w; w += NW;
    unsigned short* WkB  = w; w += NW;
    unsigned short* WvB  = w; w += NW;
    unsigned short* WoB  = w; w += NW;
    unsigned short* RWqB = w; w += 4 * NW;
    unsigned short* RWkB = w; w += 4 * NW;

    k_cvt7<<<dim3(20480), dim3(256), 0, stream>>>(hs, hsB, Wq, WqB, Wk, WkB, Wv, WvB,
                                                  Wo, WoB, RWq, RWqB, RWk, RWkB);

    GJob jq  = { WqB,  bq,  Qb,  0.125f, 0 };
    GJob jk  = { WkB,  bk,  Kb,  1.0f,   0 };
    GJob jv  = { WvB,  bv,  Vb,  1.0f,   0 };
    GJob jrq = { RWqB, Rbq, Qrb, 0.125f, 1 };
    GJob jrk = { RWkB, Rbk, Krb, 1.0f,   1 };
    k_gemm256<false><<<dim3(640), dim3(512), 0, stream>>>(hsB, jq, jk, jv, jrq, jrk, rt);

    k_vtrans<<<dim3(NB * NH * 16), dim3(256), 0, stream>>>(Vb, Vtb);
    k_attn<<<dim3(NB * NH * 8), dim3(256), 0, stream>>>(Qb, Kb, Qrb, Krb, Vtb, atb);

    GJob jo = { WoB, bo, d_out, 1.0f, 0 };
    k_gemm256<true><<<dim3(128), dim3(512), 0, stream>>>(atb, jo, jo, jo, jo, jo, nullptr);
}

// Round 12
// 240.854 us; speedup vs baseline: 1.0127x; 1.0077x over previous
//
#include <hip/hip_runtime.h>
#include <stdint.h>

#define AS1 __attribute__((address_space(1)))
#define AS3 __attribute__((address_space(3)))

typedef __attribute__((ext_vector_type(8))) short bf16x8;   // 8 bf16 = 4 VGPRs
typedef __attribute__((ext_vector_type(4))) float f32x4;

#define NB 8
#define NT 1024
#define NE 1024
#define NH 16
#define BT (NB * NT)

__device__ __forceinline__ unsigned short f2bf(float f) {
    unsigned int u = __builtin_bit_cast(unsigned int, f);
    u += 0x7FFFu + ((u >> 16) & 1u);          // RNE
    return (unsigned short)(u >> 16);
}
// pack two f32 -> one u32 of 2 bf16 (RNE) in a single VALU op
__device__ __forceinline__ unsigned int cvt_pk_bf16(float lo, float hi) {
    unsigned int r;
    asm("v_cvt_pk_bf16_f32 %0, %1, %2" : "=v"(r) : "v"(lo), "v"(hi));
    return r;
}

// ---------------- fused f32 -> bf16 conversion, 7 segments ----------------
__global__ void k_cvt7(const float* __restrict__ hs, unsigned short* __restrict__ hsB,
                       const float* __restrict__ w1, unsigned short* __restrict__ w1B,
                       const float* __restrict__ w2, unsigned short* __restrict__ w2B,
                       const float* __restrict__ w3, unsigned short* __restrict__ w3B,
                       const float* __restrict__ w4, unsigned short* __restrict__ w4B,
                       const float* __restrict__ r1, unsigned short* __restrict__ r1B,
                       const float* __restrict__ r2, unsigned short* __restrict__ r2B)
{
    int blk = blockIdx.x;
    const float* s; unsigned short* d; int base;
    if      (blk < 8192)  { s = hs; d = hsB; base = 0; }
    else if (blk < 9216)  { s = w1; d = w1B; base = 8192; }
    else if (blk < 10240) { s = w2; d = w2B; base = 9216; }
    else if (blk < 11264) { s = w3; d = w3B; base = 10240; }
    else if (blk < 12288) { s = w4; d = w4B; base = 11264; }
    else if (blk < 16384) { s = r1; d = r1B; base = 12288; }
    else                  { s = r2; d = r2B; base = 16384; }
    int i = ((blk - base) * 256 + threadIdx.x) * 4;
    float4 f = *reinterpret_cast<const float4*>(s + i);
    ushort4 o;
    o.x = f2bf(f.x); o.y = f2bf(f.y); o.z = f2bf(f.z); o.w = f2bf(f.w);
    *reinterpret_cast<ushort4*>(d + i) = o;
}

// ====== 256x128 GEMM, BK=64, 3-buffer, grid-quantization-exact ============
// proj: 5 jobs x 256 blocks = 1280 = 5 exact rounds of 256 CUs (was 640 =
// 2.5 rounds -> 17% idle tail). Wo: 256 blocks = 1 exact round (was 128 =
// half idle). 8 waves (4m x 2n), per-wave 64x64, acc[4][4]. 3 LDS buffers
// (144KB): stage t+2 into buf (t+2)%3 -- never collides with reads of t,t+1.
// vmcnt(6) once per K-tile drains exactly tile t+1 (6 instrs of 16B x 512t).
// Chunk-XOR swizzle identical to R8 (verified, conflicts == 0).
struct GJob {
    const unsigned short* W;
    const float* bias;
    void* out;
    float scale;
    int routed;
};

template <bool OUT_F32>
__global__ __launch_bounds__(512, 1)
void k_gemmN(const unsigned short* __restrict__ A,
             GJob j0, GJob j1, GJob j2, GJob j3, GJob j4,
             const int* __restrict__ rt)
{
    __shared__ __attribute__((aligned(16))) unsigned short LA[3][2][128 * 64];  // 96KB
    __shared__ __attribute__((aligned(16))) unsigned short LBb[3][128 * 64];    // 48KB

    // decode: xcd-major; per XCD 4 m-panels shared across jobs
    const int flat = blockIdx.x;
    const int xcd = flat & 7;
    const int l   = flat >> 3;          // 0..159 (proj) / 0..31 (Wo)
    const int pz  = l >> 5;             // job
    const int r   = l & 31;
    const int by  = xcd * 4 + (r >> 3); // 0..31
    const int bx  = r & 7;              // 0..7
    const int m0 = by << 8, n0 = bx << 7;

    GJob jb = j0;
    if (pz == 1) jb = j1;
    else if (pz == 2) jb = j2;
    else if (pz == 3) jb = j3;
    else if (pz == 4) jb = j4;
    int g = jb.routed ? rt[m0 >> 10] : 0;
    const unsigned short* Wg = jb.W + (size_t)g * NE * NE;

    const int tid  = threadIdx.x;
    const int wid  = tid >> 6;
    const int lane = tid & 63;
    const int frow = lane & 15;
    const int g4   = lane >> 4;
    const int wm = wid >> 1, wn = wid & 1;   // 4m x 2n

    const int rh0  = tid >> 3;                       // 0..63
    const int swz8 = ((tid & 7) ^ (rh0 & 7)) * 8;
    const unsigned short* baseA = A  + (size_t)m0 * NE;
    const unsigned short* baseB = Wg + (size_t)n0 * NE;

    // half-tile = 128 rows x 64 k = 1024 chunks = 512 thr x 2 gload (2 instrs)
    auto STAGE_A = [&](int d, int half, int kt) {
#pragma unroll
        for (int j = 0; j < 2; ++j) {
            const unsigned short* src =
                baseA + (size_t)(half * 128 + rh0 + j * 64) * NE + kt * 64 + swz8;
            __builtin_amdgcn_global_load_lds((AS1 void*)src,
                (AS3 void*)&LA[d][half][(tid + j * 512) * 8], 16, 0, 0);
        }
    };
    auto STAGE_B = [&](int d, int kt) {
#pragma unroll
        for (int j = 0; j < 2; ++j) {
            const unsigned short* src =
                baseB + (size_t)(rh0 + j * 64) * NE + kt * 64 + swz8;
            __builtin_amdgcn_global_load_lds((AS1 void*)src,
                (AS3 void*)&LBb[d][(tid + j * 512) * 8], 16, 0, 0);
        }
    };

    f32x4 acc[4][4];
#pragma unroll
    for (int m = 0; m < 4; ++m)
#pragma unroll
        for (int n = 0; n < 4; ++n) acc[m][n] = (f32x4){0.f, 0.f, 0.f, 0.f};

    bf16x8 a4[4], b4[4];
    auto RDA = [&](int d, int kh) {
#pragma unroll
        for (int mf = 0; mf < 4; ++mf) {
            int rowin = (wm & 1) * 64 + mf * 16 + frow;   // within 128-row half
            int off = rowin * 64 + (((kh * 4 + g4) ^ (frow & 7)) * 8);
            a4[mf] = *reinterpret_cast<const bf16x8*>(&LA[d][wm >> 1][off]);
        }
    };
    auto RDB = [&](int d, int kh) {
#pragma unroll
        for (int nf = 0; nf < 4; ++nf) {
            int rowin = wn * 64 + nf * 16 + frow;
            int off = rowin * 64 + (((kh * 4 + g4) ^ (frow & 7)) * 8);
            b4[nf] = *reinterpret_cast<const bf16x8*>(&LBb[d][off]);
        }
    };
    auto MM = [&]() {
        __builtin_amdgcn_s_setprio(1);
#pragma unroll
        for (int mf = 0; mf < 4; ++mf)
#pragma unroll
            for (int nf = 0; nf < 4; ++nf)
                acc[mf][nf] =
                    __builtin_amdgcn_mfma_f32_16x16x32_bf16(a4[mf], b4[nf], acc[mf][nf], 0, 0, 0);
        __builtin_amdgcn_s_setprio(0);
    };

#define BARX __builtin_amdgcn_s_barrier()
#define LGK0 asm volatile("s_waitcnt lgkmcnt(0)" ::: "memory")
#define VMC6 asm volatile("s_waitcnt vmcnt(6)" ::: "memory")
#define VMC0 asm volatile("s_waitcnt vmcnt(0)" ::: "memory")

    // prologue: tiles 0,1 into bufs 0,1 (12 instrs); drain tile 0 (->6)
    STAGE_A(0, 0, 0); STAGE_A(0, 1, 0); STAGE_B(0, 0);
    STAGE_A(1, 0, 1); STAGE_A(1, 1, 1); STAGE_B(1, 1);
    VMC6; BARX;

    int bt = 0;
#pragma unroll 1
    for (int t = 0; t < 16; ++t) {
        const int b2 = (bt + 2 >= 3) ? bt - 1 : bt + 2;   // (t+2)%3
        const bool pre = (t + 2 < 16);
        // ph0: read kh0 | issue Ah0(t+2)
        RDA(bt, 0); RDB(bt, 0);
        if (pre) STAGE_A(b2, 0, t + 2);
        BARX; LGK0; MM(); BARX;
        // ph1: read kh1 | issue Ah1(t+2)+B(t+2) | drain t+1 (12 -> 6)
        RDA(bt, 1); RDB(bt, 1);
        if (pre) { STAGE_A(b2, 1, t + 2); STAGE_B(b2, t + 2); }
        BARX; LGK0; MM();
        if (t < 14) { VMC6; } else if (t == 14) { VMC0; }
        BARX;
        bt = (bt + 1 >= 3) ? 0 : bt + 1;
    }
#undef BARX
#undef LGK0
#undef VMC6
#undef VMC0

    const float* biasg = jb.bias + (size_t)g * NE;
#pragma unroll
    for (int am = 0; am < 4; ++am) {
        int row = m0 + wm * 64 + am * 16 + g4 * 4;
#pragma unroll
        for (int nf = 0; nf < 4; ++nf) {
            int col = n0 + wn * 64 + nf * 16 + frow;
            float bv = biasg[col];
            f32x4 v = acc[am][nf];
#pragma unroll
            for (int r2 = 0; r2 < 4; ++r2) {
                float val = (v[r2] + bv) * jb.scale;
                if (OUT_F32)
                    ((float*)jb.out)[(size_t)(row + r2) * NE + col] = val;
                else
                    ((unsigned short*)jb.out)[(size_t)(row + r2) * NE + col] = f2bf(val);
            }
        }
    }
}

// ---------------- V transpose: Vt[(b,h),d,s] = V[b,s,h*64+d] ----------------
__global__ void k_vtrans(const unsigned short* __restrict__ V, unsigned short* __restrict__ Vt) {
    __shared__ unsigned short tile[64][65];
    const int blk = blockIdx.x;
    const int bh = blk >> 4;
    const int b = bh >> 4;
    const int h = bh & 15;
    const int s0 = (blk & 15) * 64;
    const int tid = threadIdx.x;
#pragma unroll
    for (int i = 0; i < 2; ++i) {
        int seg = tid + i * 256;
        int row = seg >> 3;
        int c8 = (seg & 7) * 8;
        const unsigned short* src = V + (size_t)(b * NT + s0 + row) * NE + h * 64 + c8;
        ushort4 u0 = *reinterpret_cast<const ushort4*>(src);
        ushort4 u1 = *reinterpret_cast<const ushort4*>(src + 4);
        tile[row][c8 + 0] = u0.x; tile[row][c8 + 1] = u0.y;
        tile[row][c8 + 2] = u0.z; tile[row][c8 + 3] = u0.w;
        tile[row][c8 + 4] = u1.x; tile[row][c8 + 5] = u1.y;
        tile[row][c8 + 6] = u1.z; tile[row][c8 + 7] = u1.w;
    }
    __syncthreads();
#pragma unroll
    for (int i = 0; i < 2; ++i) {
        int seg = tid + i * 256;
        int drow = seg >> 3;
        int s8 = (seg & 7) * 8;
        ushort4 u0, u1;
        u0.x = tile[s8 + 0][drow]; u0.y = tile[s8 + 1][drow];
        u0.z = tile[s8 + 2][drow]; u0.w = tile[s8 + 3][drow];
        u1.x = tile[s8 + 4][drow]; u1.y = tile[s8 + 5][drow];
        u1.z = tile[s8 + 6][drow]; u1.w = tile[s8 + 7][drow];
        unsigned short* dst = Vt + (size_t)(bh * 64 + drow) * NT + s0 + s8;
        *reinterpret_cast<ushort4*>(dst) = u0;
        *reinterpret_cast<ushort4*>(dst + 4) = u1;
    }
}

// ---------------- fused dual-stream attention (R7 version, proven ~90us) ----
__global__ __launch_bounds__(512, 4)
void k_attn(const unsigned short* __restrict__ Q,
            const unsigned short* __restrict__ K,
            const unsigned short* __restrict__ Qr,
            const unsigned short* __restrict__ Kr,
            const unsigned short* __restrict__ Vt,
            unsigned short* __restrict__ attnO)
{
    constexpr int PLD = 40;   // 80B rows (16B-aligned); half-tile = 16 rows x 32 s
    __shared__ __attribute__((aligned(16))) unsigned short KV[2][3 * 4096];   // Kg|Kr|V 8KB each
    __shared__ __attribute__((aligned(16))) unsigned short Pga[8][16 * PLD];  // per-wave Pg half
    __shared__ __attribute__((aligned(16))) unsigned short Pra[8][16 * PLD];  // per-wave Pr half

    const int blk = (blockIdx.x & 7) * 128 + (blockIdx.x >> 3);
    const int tile = blk & 7;
    const int bh = blk >> 3;
    const int b = bh >> 4;
    const int h = bh & 15;
    const int wid = threadIdx.x >> 6;
    const int lane = threadIdx.x & 63;
    const int frow = lane & 15;
    const int g4 = lane >> 4;
    const int f7 = frow & 7;
    const int fk8 = g4 * 8;
    const int t0 = tile * 128 + wid * 16;

    const size_t qoff = (size_t)(b * NT + t0 + frow) * NE + h * 64;
    const bf16x8 qf0 = *reinterpret_cast<const bf16x8*>(Q + qoff + fk8);
    const bf16x8 qf1 = *reinterpret_cast<const bf16x8*>(Q + qoff + 32 + fk8);
    const bf16x8 qr0 = *reinterpret_cast<const bf16x8*>(Qr + qoff + fk8);
    const bf16x8 qr1 = *reinterpret_cast<const bf16x8*>(Qr + qoff + 32 + fk8);

    const unsigned short* Kb  = K  + (size_t)b * NT * NE + h * 64;
    const unsigned short* Krb = Kr + (size_t)b * NT * NE + h * 64;
    const unsigned short* Vtb = Vt + (size_t)bh * 64 * NT;
    unsigned short* PgRow = &Pga[wid][0] + frow * PLD;
    unsigned short* PrRow = &Pra[wid][0] + frow * PLD;

    f32x4 og[4], orr[4];
    float lgp = 0.f, lrp = 0.f;
#pragma unroll
    for (int i = 0; i < 4; ++i) {
        og[i] = (f32x4){0.f, 0.f, 0.f, 0.f};
        orr[i] = (f32x4){0.f, 0.f, 0.f, 0.f};
    }

    const int srow = threadIdx.x >> 3;                         // 0..63
    const int scb8 = ((threadIdx.x & 7) ^ (srow & 7)) * 8;
    auto stage = [&](int buf, int s0) {
        const unsigned short* sK = Kb  + (size_t)(s0 + srow) * NE + scb8;
        const unsigned short* sR = Krb + (size_t)(s0 + srow) * NE + scb8;
        const unsigned short* sV = Vtb + (size_t)srow * NT + s0 + scb8;
        __builtin_amdgcn_global_load_lds((AS1 void*)sK, (AS3 void*)(&KV[buf][wid * 512]), 16, 0, 0);
        __builtin_amdgcn_global_load_lds((AS1 void*)sR, (AS3 void*)(&KV[buf][4096 + wid * 512]), 16, 0, 0);
        __builtin_amdgcn_global_load_lds((AS1 void*)sV, (AS3 void*)(&KV[buf][8192 + wid * 512]), 16, 0, 0);
    };

    stage(0, 0);
    __syncthreads();
    int cur = 0;
    const f32x4 z = (f32x4){0.f, 0.f, 0.f, 0.f};
#pragma unroll 1
    for (int t = 0; t < NT / 64; ++t) {
        if (t < NT / 64 - 1) stage(cur ^ 1, (t + 1) * 64);
        const unsigned short* Kl  = &KV[cur][0];
        const unsigned short* Krl = &KV[cur][4096];
        const unsigned short* Vl  = &KV[cur][8192];

        // QK^T swapped: sg[nf] lane = S[q=frow][s=16nf+4g4+r]
        f32x4 sg[4], sr[4];
#pragma unroll
        for (int nf = 0; nf < 4; ++nf) {
            const int ro = (nf * 16 + frow) * 64;
            bf16x8 kA = *reinterpret_cast<const bf16x8*>(Kl + ro + ((g4 ^ f7) * 8));
            bf16x8 kB = *reinterpret_cast<const bf16x8*>(Kl + ro + (((4 + g4) ^ f7) * 8));
            bf16x8 rA = *reinterpret_cast<const bf16x8*>(Krl + ro + ((g4 ^ f7) * 8));
            bf16x8 rB = *reinterpret_cast<const bf16x8*>(Krl + ro + (((4 + g4) ^ f7) * 8));
            sg[nf] = __builtin_amdgcn_mfma_f32_16x16x32_bf16(kA, qf0, z, 0, 0, 0);
            sg[nf] = __builtin_amdgcn_mfma_f32_16x16x32_bf16(kB, qf1, sg[nf], 0, 0, 0);
            sr[nf] = __builtin_amdgcn_mfma_f32_16x16x32_bf16(rA, qr0, z, 0, 0, 0);
            sr[nf] = __builtin_amdgcn_mfma_f32_16x16x32_bf16(rB, qr1, sr[nf], 0, 0, 0);
        }

        // two s-halves: pack both streams, one wait, PV with shared V-frags
#pragma unroll
        for (int hh = 0; hh < 2; ++hh) {
#pragma unroll
            for (int j = 0; j < 2; ++j) {
                const int nf = 2 * hh + j;
                float g0 = __expf(sg[nf][0]), g1 = __expf(sg[nf][1]);
                float g2 = __expf(sg[nf][2]), g3 = __expf(sg[nf][3]);
                lgp += (g0 + g1) + (g2 + g3);
                uint2 wg;
                wg.x = cvt_pk_bf16(g0, g1);
                wg.y = cvt_pk_bf16(g2, g3);
                *reinterpret_cast<uint2*>(PgRow + j * 16 + g4 * 4) = wg;
                float r0 = __expf(sr[nf][0]), r1 = __expf(sr[nf][1]);
                float r2 = __expf(sr[nf][2]), r3 = __expf(sr[nf][3]);
                lrp += (r0 + r1) + (r2 + r3);
                uint2 wr;
                wr.x = cvt_pk_bf16(r0, r1);
                wr.y = cvt_pk_bf16(r2, r3);
                *reinterpret_cast<uint2*>(PrRow + j * 16 + g4 * 4) = wr;
            }
            asm volatile("s_waitcnt lgkmcnt(0)" ::: "memory");   // P visible (same wave)
            bf16x8 pg = *reinterpret_cast<const bf16x8*>(PgRow + fk8);
            bf16x8 pr = *reinterpret_cast<const bf16x8*>(PrRow + fk8);
            __builtin_amdgcn_s_setprio(1);
#pragma unroll
            for (int nf2 = 0; nf2 < 4; ++nf2) {
                const int vo = (nf2 * 16 + frow) * 64;
                bf16x8 v = *reinterpret_cast<const bf16x8*>(Vl + vo + (((4 * hh + g4) ^ f7) * 8));
                og[nf2]  = __builtin_amdgcn_mfma_f32_16x16x32_bf16(pg, v, og[nf2], 0, 0, 0);
                orr[nf2] = __builtin_amdgcn_mfma_f32_16x16x32_bf16(pr, v, orr[nf2], 0, 0, 0);
            }
            __builtin_amdgcn_s_setprio(0);
        }

        __syncthreads();   // drains vmcnt (next KV tile staged) + overwrite fence
        cur ^= 1;
    }

    // full row sums for q-row frow (reduce across the 4 g4 lanes)
    lgp += __shfl_xor(lgp, 16); lgp += __shfl_xor(lgp, 32);
    lrp += __shfl_xor(lrp, 16); lrp += __shfl_xor(lrp, 32);
    float ig = 0.45f / lgp, ir = 0.05f / lrp;
    float igr[4], irr[4];
#pragma unroll
    for (int r = 0; r < 4; ++r) {
        igr[r] = __shfl(ig, g4 * 4 + r);
        irr[r] = __shfl(ir, g4 * 4 + r);
    }
#pragma unroll
    for (int nf2 = 0; nf2 < 4; ++nf2) {
#pragma unroll
        for (int r = 0; r < 4; ++r) {
            float val = og[nf2][r] * igr[r] + orr[nf2][r] * irr[r];
            int tq = t0 + g4 * 4 + r;
            attnO[(size_t)(b * NT + tq) * NE + h * 64 + nf2 * 16 + frow] = f2bf(val);
        }
    }
}

// ---------------- launcher ----------------
extern "C" void kernel_launch(void* const* d_in, const int* in_sizes, int n_in,
                              void* d_out, int out_size, void* d_ws, size_t ws_size,
                              hipStream_t stream)
{
    const float* hs  = (const float*)d_in[0];
    const int*   rt  = (const int*)d_in[1];
    const float* Wq  = (const float*)d_in[2];
    const float* bq  = (const float*)d_in[3];
    const float* Wk  = (const float*)d_in[4];
    const float* bk  = (const float*)d_in[5];
    const float* Wv  = (const float*)d_in[6];
    const float* bv  = (const float*)d_in[7];
    const float* Wo  = (const float*)d_in[8];
    const float* bo  = (const float*)d_in[9];
    const float* RWq = (const float*)d_in[10];
    const float* Rbq = (const float*)d_in[11];
    const float* RWk = (const float*)d_in[12];
    const float* Rbk = (const float*)d_in[13];

    unsigned short* w = (unsigned short*)d_ws;
    const size_t NBT = (size_t)BT * NE;   // 8M elems
    const size_t NW  = (size_t)NE * NE;   // 1M elems
    unsigned short* hsB  = w; w += NBT;
    unsigned short* Qb   = w; w += NBT;
    unsigned short* Kb   = w; w += NBT;
    unsigned short* Vb   = w; w += NBT;
    unsigned short* Qrb  = w; w += NBT;
    unsigned short* Krb  = w; w += NBT;
    unsigned short* Vtb  = w; w += NBT;
    unsigned short* atb  = w; w += NBT;
    unsigned short* WqB  = w; w += NW;
    unsigned short* WkB  = w; w += NW;
    unsigned short* WvB  = w; w += NW;
    unsigned short* WoB  = w; w += NW;
    unsigned short* RWqB = w; w += 4 * NW;
    unsigned short* RWkB = w; w += 4 * NW;

    k_cvt7<<<dim3(20480), dim3(256), 0, stream>>>(hs, hsB, Wq, WqB, Wk, WkB, Wv, WvB,
                                                  Wo, WoB, RWq, RWqB, RWk, RWkB);

    GJob jq  = { WqB,  bq,  Qb,  0.125f, 0 };
    GJob jk  = { WkB,  bk,  Kb,  1.0f,   0 };
    GJob jv  = { WvB,  bv,  Vb,  1.0f,   0 };
    GJob jrq = { RWqB, Rbq, Qrb, 0.125f, 1 };
    GJob jrk = { RWkB, Rbk, Krb, 1.0f,   1 };
    k_gemmN<false><<<dim3(1280), dim3(512), 0, stream>>>(hsB, jq, jk, jv, jrq, jrk, rt);

    k_vtrans<<<dim3(NB * NH * 16), dim3(256), 0, stream>>>(Vb, Vtb);
    k_attn<<<dim3(NB * NH * 8), dim3(512), 0, stream>>>(Qb, Kb, Qrb, Krb, Vtb, atb);

    GJob jo = { WoB, bo, d_out, 1.0f, 0 };
    k_gemmN<true><<<dim3(256), dim3(512), 0, stream>>>(atb, jo, jo, jo, jo, jo, nullptr);
}

// Round 13
// 231.879 us; speedup vs baseline: 1.0519x; 1.0387x over previous
//
#include <hip/hip_runtime.h>
#include <stdint.h>

#define AS1 __attribute__((address_space(1)))
#define AS3 __attribute__((address_space(3)))

typedef __attribute__((ext_vector_type(8))) short bf16x8;   // 8 bf16 = 4 VGPRs
typedef __attribute__((ext_vector_type(4))) float f32x4;

#define NB 8
#define NT 1024
#define NE 1024
#define NH 16
#define BT (NB * NT)

__device__ __forceinline__ unsigned short f2bf(float f) {
    unsigned int u = __builtin_bit_cast(unsigned int, f);
    u += 0x7FFFu + ((u >> 16) & 1u);          // RNE
    return (unsigned short)(u >> 16);
}
// pack two f32 -> one u32 of 2 bf16 (RNE) in a single VALU op
__device__ __forceinline__ unsigned int cvt_pk_bf16(float lo, float hi) {
    unsigned int r;
    asm("v_cvt_pk_bf16_f32 %0, %1, %2" : "=v"(r) : "v"(lo), "v"(hi));
    return r;
}

// ---------------- fused f32 -> bf16 conversion, 7 segments ----------------
__global__ void k_cvt7(const float* __restrict__ hs, unsigned short* __restrict__ hsB,
                       const float* __restrict__ w1, unsigned short* __restrict__ w1B,
                       const float* __restrict__ w2, unsigned short* __restrict__ w2B,
                       const float* __restrict__ w3, unsigned short* __restrict__ w3B,
                       const float* __restrict__ w4, unsigned short* __restrict__ w4B,
                       const float* __restrict__ r1, unsigned short* __restrict__ r1B,
                       const float* __restrict__ r2, unsigned short* __restrict__ r2B)
{
    int blk = blockIdx.x;
    const float* s; unsigned short* d; int base;
    if      (blk < 8192)  { s = hs; d = hsB; base = 0; }
    else if (blk < 9216)  { s = w1; d = w1B; base = 8192; }
    else if (blk < 10240) { s = w2; d = w2B; base = 9216; }
    else if (blk < 11264) { s = w3; d = w3B; base = 10240; }
    else if (blk < 12288) { s = w4; d = w4B; base = 11264; }
    else if (blk < 16384) { s = r1; d = r1B; base = 12288; }
    else                  { s = r2; d = r2B; base = 16384; }
    int i = ((blk - base) * 256 + threadIdx.x) * 4;
    float4 f = *reinterpret_cast<const float4*>(s + i);
    ushort4 o;
    o.x = f2bf(f.x); o.y = f2bf(f.y); o.z = f2bf(f.z); o.w = f2bf(f.w);
    *reinterpret_cast<ushort4*>(d + i) = o;
}

struct GJob {
    const unsigned short* W;
    const float* bias;
    void* out;
    float scale;
    int routed;
};

// ============ 256x256 8-phase GEMM (R8 verified: proj dispatch) ============
template <bool OUT_F32>
__global__ __launch_bounds__(512, 2)
void k_gemm256(const unsigned short* __restrict__ A,
               GJob j0, GJob j1, GJob j2, GJob j3, GJob j4,
               const int* __restrict__ rt)
{
    __shared__ __attribute__((aligned(16))) unsigned short LB[2][2][2][128 * 64];

    const int flat = blockIdx.x;
    const int xcd = flat & 7;           // consecutive blocks round-robin XCDs
    const int l   = flat >> 3;          // sequence within this XCD
    const int pz  = l >> 4;             // job
    const int r   = l & 15;
    const int by  = xcd * 4 + (r >> 2); // 4 m-panels per XCD, all jobs
    const int bx  = r & 3;
    const int m0 = by << 8, n0 = bx << 8;

    GJob jb = j0;
    if (pz == 1) jb = j1;
    else if (pz == 2) jb = j2;
    else if (pz == 3) jb = j3;
    else if (pz == 4) jb = j4;
    int g = jb.routed ? rt[m0 >> 10] : 0;
    const unsigned short* Wg = jb.W + (size_t)g * NE * NE;

    const int tid  = threadIdx.x;
    const int wid  = tid >> 6;
    const int lane = tid & 63;
    const int frow = lane & 15;
    const int g4   = lane >> 4;
    const int wm = wid >> 2, wn = wid & 3;

    const int rh0  = tid >> 3;
    const int swz8 = ((tid & 7) ^ (rh0 & 7)) * 8;
    const unsigned short* baseA = A  + (size_t)m0 * NE;
    const unsigned short* baseB = Wg + (size_t)n0 * NE;

    auto STAGE = [&](int d, int mat, int half, int kt) {
        const unsigned short* base = mat ? baseB : baseA;
#pragma unroll
        for (int j = 0; j < 2; ++j) {
            const unsigned short* src =
                base + (size_t)(half * 128 + rh0 + j * 64) * NE + kt * 64 + swz8;
            __builtin_amdgcn_global_load_lds((AS1 void*)src,
                (AS3 void*)&LB[d][mat][half][(wid * 64 + j * 512) * 8], 16, 0, 0);
        }
    };

    f32x4 acc[8][4];
#pragma unroll
    for (int m = 0; m < 8; ++m)
#pragma unroll
        for (int n = 0; n < 4; ++n) acc[m][n] = (f32x4){0.f, 0.f, 0.f, 0.f};

    bf16x8 a4[4], b4[4];
    auto RDA = [&](int d, int mh, int kh) {
#pragma unroll
        for (int mf = 0; mf < 4; ++mf) {
            int rh = mh * 64 + mf * 16 + frow;
            int off = rh * 64 + (((kh * 4 + g4) ^ (frow & 7)) * 8);
            a4[mf] = *reinterpret_cast<const bf16x8*>(&LB[d][0][wm][off]);
        }
    };
    auto RDB = [&](int d, int kh) {
#pragma unroll
        for (int nf = 0; nf < 4; ++nf) {
            int rh = (wn & 1) * 64 + nf * 16 + frow;
            int off = rh * 64 + (((kh * 4 + g4) ^ (frow & 7)) * 8);
            b4[nf] = *reinterpret_cast<const bf16x8*>(&LB[d][1][wn >> 1][off]);
        }
    };
    auto MM = [&](int mh) {
        __builtin_amdgcn_s_setprio(1);
#pragma unroll
        for (int mf = 0; mf < 4; ++mf)
#pragma unroll
            for (int nf = 0; nf < 4; ++nf)
                acc[mh * 4 + mf][nf] =
                    __builtin_amdgcn_mfma_f32_16x16x32_bf16(a4[mf], b4[nf], acc[mh * 4 + mf][nf], 0, 0, 0);
        __builtin_amdgcn_s_setprio(0);
    };

#define BARX __builtin_amdgcn_s_barrier()
#define LGK0 asm volatile("s_waitcnt lgkmcnt(0)" ::: "memory")
#define VMC2 asm volatile("s_waitcnt vmcnt(2)" ::: "memory")

    STAGE(0, 0, 0, 0); STAGE(0, 0, 1, 0); STAGE(0, 1, 0, 0); STAGE(0, 1, 1, 0);
    STAGE(1, 1, 0, 1);
    VMC2; BARX;

#pragma unroll 1
    for (int i = 0; i < 8; ++i) {
        const int t = 2 * i;
        const bool pre = (i < 7);
        RDA(0, 0, 0); RDB(0, 0); STAGE(1, 1, 1, t + 1);
        BARX; LGK0; MM(0); BARX;
        RDA(0, 1, 0); STAGE(1, 0, 0, t + 1);
        BARX; LGK0; MM(1); BARX;
        RDA(0, 0, 1); RDB(0, 1); STAGE(1, 0, 1, t + 1);
        BARX; LGK0; MM(0); BARX;
        RDA(0, 1, 1); if (pre) STAGE(0, 1, 0, t + 2);
        BARX; LGK0; MM(1); VMC2; BARX;
        RDA(1, 0, 0); RDB(1, 0); if (pre) STAGE(0, 1, 1, t + 2);
        BARX; LGK0; MM(0); BARX;
        RDA(1, 1, 0); if (pre) STAGE(0, 0, 0, t + 2);
        BARX; LGK0; MM(1); BARX;
        RDA(1, 0, 1); RDB(1, 1); if (pre) STAGE(0, 0, 1, t + 2);
        BARX; LGK0; MM(0); BARX;
        RDA(1, 1, 1); if (pre) STAGE(1, 1, 0, t + 3);
        BARX; LGK0; MM(1); VMC2; BARX;
    }
#undef BARX
#undef LGK0
#undef VMC2

    const float* biasg = jb.bias + (size_t)(jb.routed ? (rt[m0 >> 10]) : 0) * NE;
#pragma unroll
    for (int am = 0; am < 8; ++am) {
        int row = m0 + wm * 128 + am * 16 + g4 * 4;
#pragma unroll
        for (int nf = 0; nf < 4; ++nf) {
            int col = n0 + wn * 64 + nf * 16 + frow;
            float bv = biasg[col];
            f32x4 v = acc[am][nf];
#pragma unroll
            for (int r2 = 0; r2 < 4; ++r2) {
                float val = (v[r2] + bv) * jb.scale;
                if (OUT_F32)
                    ((float*)jb.out)[(size_t)(row + r2) * NE + col] = val;
                else
                    ((unsigned short*)jb.out)[(size_t)(row + r2) * NE + col] = f2bf(val);
            }
        }
    }
}

// ====== 256x128 GEMM, BK=64, 3-buffer (R12 verified: Wo, exact 256 grid) ===
template <bool OUT_F32>
__global__ __launch_bounds__(512, 1)
void k_gemmN(const unsigned short* __restrict__ A,
             GJob j0, GJob j1, GJob j2, GJob j3, GJob j4,
             const int* __restrict__ rt)
{
    __shared__ __attribute__((aligned(16))) unsigned short LA[3][2][128 * 64];  // 96KB
    __shared__ __attribute__((aligned(16))) unsigned short LBb[3][128 * 64];    // 48KB

    const int flat = blockIdx.x;
    const int xcd = flat & 7;
    const int l   = flat >> 3;
    const int pz  = l >> 5;
    const int r   = l & 31;
    const int by  = xcd * 4 + (r >> 3);
    const int bx  = r & 7;
    const int m0 = by << 8, n0 = bx << 7;

    GJob jb = j0;
    if (pz == 1) jb = j1;
    else if (pz == 2) jb = j2;
    else if (pz == 3) jb = j3;
    else if (pz == 4) jb = j4;
    int g = jb.routed ? rt[m0 >> 10] : 0;
    const unsigned short* Wg = jb.W + (size_t)g * NE * NE;

    const int tid  = threadIdx.x;
    const int wid  = tid >> 6;
    const int lane = tid & 63;
    const int frow = lane & 15;
    const int g4   = lane >> 4;
    const int wm = wid >> 1, wn = wid & 1;   // 4m x 2n

    const int rh0  = tid >> 3;
    const int swz8 = ((tid & 7) ^ (rh0 & 7)) * 8;
    const unsigned short* baseA = A  + (size_t)m0 * NE;
    const unsigned short* baseB = Wg + (size_t)n0 * NE;

    auto STAGE_A = [&](int d, int half, int kt) {
#pragma unroll
        for (int j = 0; j < 2; ++j) {
            const unsigned short* src =
                baseA + (size_t)(half * 128 + rh0 + j * 64) * NE + kt * 64 + swz8;
            __builtin_amdgcn_global_load_lds((AS1 void*)src,
                (AS3 void*)&LA[d][half][(tid + j * 512) * 8], 16, 0, 0);
        }
    };
    auto STAGE_B = [&](int d, int kt) {
#pragma unroll
        for (int j = 0; j < 2; ++j) {
            const unsigned short* src =
                baseB + (size_t)(rh0 + j * 64) * NE + kt * 64 + swz8;
            __builtin_amdgcn_global_load_lds((AS1 void*)src,
                (AS3 void*)&LBb[d][(tid + j * 512) * 8], 16, 0, 0);
        }
    };

    f32x4 acc[4][4];
#pragma unroll
    for (int m = 0; m < 4; ++m)
#pragma unroll
        for (int n = 0; n < 4; ++n) acc[m][n] = (f32x4){0.f, 0.f, 0.f, 0.f};

    bf16x8 a4[4], b4[4];
    auto RDA = [&](int d, int kh) {
#pragma unroll
        for (int mf = 0; mf < 4; ++mf) {
            int rowin = (wm & 1) * 64 + mf * 16 + frow;
            int off = rowin * 64 + (((kh * 4 + g4) ^ (frow & 7)) * 8);
            a4[mf] = *reinterpret_cast<const bf16x8*>(&LA[d][wm >> 1][off]);
        }
    };
    auto RDB = [&](int d, int kh) {
#pragma unroll
        for (int nf = 0; nf < 4; ++nf) {
            int rowin = wn * 64 + nf * 16 + frow;
            int off = rowin * 64 + (((kh * 4 + g4) ^ (frow & 7)) * 8);
            b4[nf] = *reinterpret_cast<const bf16x8*>(&LBb[d][off]);
        }
    };
    auto MM = [&]() {
        __builtin_amdgcn_s_setprio(1);
#pragma unroll
        for (int mf = 0; mf < 4; ++mf)
#pragma unroll
            for (int nf = 0; nf < 4; ++nf)
                acc[mf][nf] =
                    __builtin_amdgcn_mfma_f32_16x16x32_bf16(a4[mf], b4[nf], acc[mf][nf], 0, 0, 0);
        __builtin_amdgcn_s_setprio(0);
    };

#define BARX __builtin_amdgcn_s_barrier()
#define LGK0 asm volatile("s_waitcnt lgkmcnt(0)" ::: "memory")
#define VMC6 asm volatile("s_waitcnt vmcnt(6)" ::: "memory")
#define VMC0 asm volatile("s_waitcnt vmcnt(0)" ::: "memory")

    STAGE_A(0, 0, 0); STAGE_A(0, 1, 0); STAGE_B(0, 0);
    STAGE_A(1, 0, 1); STAGE_A(1, 1, 1); STAGE_B(1, 1);
    VMC6; BARX;

    int bt = 0;
#pragma unroll 1
    for (int t = 0; t < 16; ++t) {
        const int b2 = (bt + 2 >= 3) ? bt - 1 : bt + 2;   // (t+2)%3
        const bool pre = (t + 2 < 16);
        RDA(bt, 0); RDB(bt, 0);
        if (pre) STAGE_A(b2, 0, t + 2);
        BARX; LGK0; MM(); BARX;
        RDA(bt, 1); RDB(bt, 1);
        if (pre) { STAGE_A(b2, 1, t + 2); STAGE_B(b2, t + 2); }
        BARX; LGK0; MM();
        if (t < 14) { VMC6; } else if (t == 14) { VMC0; }
        BARX;
        bt = (bt + 1 >= 3) ? 0 : bt + 1;
    }
#undef BARX
#undef LGK0
#undef VMC6
#undef VMC0

    const float* biasg = jb.bias + (size_t)g * NE;
#pragma unroll
    for (int am = 0; am < 4; ++am) {
        int row = m0 + wm * 64 + am * 16 + g4 * 4;
#pragma unroll
        for (int nf = 0; nf < 4; ++nf) {
            int col = n0 + wn * 64 + nf * 16 + frow;
            float bv = biasg[col];
            f32x4 v = acc[am][nf];
#pragma unroll
            for (int r2 = 0; r2 < 4; ++r2) {
                float val = (v[r2] + bv) * jb.scale;
                if (OUT_F32)
                    ((float*)jb.out)[(size_t)(row + r2) * NE + col] = val;
                else
                    ((unsigned short*)jb.out)[(size_t)(row + r2) * NE + col] = f2bf(val);
            }
        }
    }
}

// ---------------- V transpose: Vt[(b,h),d,s] = V[b,s,h*64+d] ----------------
__global__ void k_vtrans(const unsigned short* __restrict__ V, unsigned short* __restrict__ Vt) {
    __shared__ unsigned short tile[64][65];
    const int blk = blockIdx.x;
    const int bh = blk >> 4;
    const int b = bh >> 4;
    const int h = bh & 15;
    const int s0 = (blk & 15) * 64;
    const int tid = threadIdx.x;
#pragma unroll
    for (int i = 0; i < 2; ++i) {
        int seg = tid + i * 256;
        int row = seg >> 3;
        int c8 = (seg & 7) * 8;
        const unsigned short* src = V + (size_t)(b * NT + s0 + row) * NE + h * 64 + c8;
        ushort4 u0 = *reinterpret_cast<const ushort4*>(src);
        ushort4 u1 = *reinterpret_cast<const ushort4*>(src + 4);
        tile[row][c8 + 0] = u0.x; tile[row][c8 + 1] = u0.y;
        tile[row][c8 + 2] = u0.z; tile[row][c8 + 3] = u0.w;
        tile[row][c8 + 4] = u1.x; tile[row][c8 + 5] = u1.y;
        tile[row][c8 + 6] = u1.z; tile[row][c8 + 7] = u1.w;
    }
    __syncthreads();
#pragma unroll
    for (int i = 0; i < 2; ++i) {
        int seg = tid + i * 256;
        int drow = seg >> 3;
        int s8 = (seg & 7) * 8;
        ushort4 u0, u1;
        u0.x = tile[s8 + 0][drow]; u0.y = tile[s8 + 1][drow];
        u0.z = tile[s8 + 2][drow]; u0.w = tile[s8 + 3][drow];
        u1.x = tile[s8 + 4][drow]; u1.y = tile[s8 + 5][drow];
        u1.z = tile[s8 + 6][drow]; u1.w = tile[s8 + 7][drow];
        unsigned short* dst = Vt + (size_t)(bh * 64 + drow) * NT + s0 + s8;
        *reinterpret_cast<ushort4*>(dst) = u0;
        *reinterpret_cast<ushort4*>(dst + 4) = u1;
    }
}

// ---------------- fused dual-stream attention (R7 verified, ~75-90us) -------
__global__ __launch_bounds__(512, 4)
void k_attn(const unsigned short* __restrict__ Q,
            const unsigned short* __restrict__ K,
            const unsigned short* __restrict__ Qr,
            const unsigned short* __restrict__ Kr,
            const unsigned short* __restrict__ Vt,
            unsigned short* __restrict__ attnO)
{
    constexpr int PLD = 40;   // 80B rows (16B-aligned); half-tile = 16 rows x 32 s
    __shared__ __attribute__((aligned(16))) unsigned short KV[2][3 * 4096];   // Kg|Kr|V 8KB each
    __shared__ __attribute__((aligned(16))) unsigned short Pga[8][16 * PLD];  // per-wave Pg half
    __shared__ __attribute__((aligned(16))) unsigned short Pra[8][16 * PLD];  // per-wave Pr half

    const int blk = (blockIdx.x & 7) * 128 + (blockIdx.x >> 3);
    const int tile = blk & 7;
    const int bh = blk >> 3;
    const int b = bh >> 4;
    const int h = bh & 15;
    const int wid = threadIdx.x >> 6;
    const int lane = threadIdx.x & 63;
    const int frow = lane & 15;
    const int g4 = lane >> 4;
    const int f7 = frow & 7;
    const int fk8 = g4 * 8;
    const int t0 = tile * 128 + wid * 16;

    const size_t qoff = (size_t)(b * NT + t0 + frow) * NE + h * 64;
    const bf16x8 qf0 = *reinterpret_cast<const bf16x8*>(Q + qoff + fk8);
    const bf16x8 qf1 = *reinterpret_cast<const bf16x8*>(Q + qoff + 32 + fk8);
    const bf16x8 qr0 = *reinterpret_cast<const bf16x8*>(Qr + qoff + fk8);
    const bf16x8 qr1 = *reinterpret_cast<const bf16x8*>(Qr + qoff + 32 + fk8);

    const unsigned short* Kb  = K  + (size_t)b * NT * NE + h * 64;
    const unsigned short* Krb = Kr + (size_t)b * NT * NE + h * 64;
    const unsigned short* Vtb = Vt + (size_t)bh * 64 * NT;
    unsigned short* PgRow = &Pga[wid][0] + frow * PLD;
    unsigned short* PrRow = &Pra[wid][0] + frow * PLD;

    f32x4 og[4], orr[4];
    float lgp = 0.f, lrp = 0.f;
#pragma unroll
    for (int i = 0; i < 4; ++i) {
        og[i] = (f32x4){0.f, 0.f, 0.f, 0.f};
        orr[i] = (f32x4){0.f, 0.f, 0.f, 0.f};
    }

    const int srow = threadIdx.x >> 3;                         // 0..63
    const int scb8 = ((threadIdx.x & 7) ^ (srow & 7)) * 8;
    auto stage = [&](int buf, int s0) {
        const unsigned short* sK = Kb  + (size_t)(s0 + srow) * NE + scb8;
        const unsigned short* sR = Krb + (size_t)(s0 + srow) * NE + scb8;
        const unsigned short* sV = Vtb + (size_t)srow * NT + s0 + scb8;
        __builtin_amdgcn_global_load_lds((AS1 void*)sK, (AS3 void*)(&KV[buf][wid * 512]), 16, 0, 0);
        __builtin_amdgcn_global_load_lds((AS1 void*)sR, (AS3 void*)(&KV[buf][4096 + wid * 512]), 16, 0, 0);
        __builtin_amdgcn_global_load_lds((AS1 void*)sV, (AS3 void*)(&KV[buf][8192 + wid * 512]), 16, 0, 0);
    };

    stage(0, 0);
    __syncthreads();
    int cur = 0;
    const f32x4 z = (f32x4){0.f, 0.f, 0.f, 0.f};
#pragma unroll 1
    for (int t = 0; t < NT / 64; ++t) {
        if (t < NT / 64 - 1) stage(cur ^ 1, (t + 1) * 64);
        const unsigned short* Kl  = &KV[cur][0];
        const unsigned short* Krl = &KV[cur][4096];
        const unsigned short* Vl  = &KV[cur][8192];

        f32x4 sg[4], sr[4];
#pragma unroll
        for (int nf = 0; nf < 4; ++nf) {
            const int ro = (nf * 16 + frow) * 64;
            bf16x8 kA = *reinterpret_cast<const bf16x8*>(Kl + ro + ((g4 ^ f7) * 8));
            bf16x8 kB = *reinterpret_cast<const bf16x8*>(Kl + ro + (((4 + g4) ^ f7) * 8));
            bf16x8 rA = *reinterpret_cast<const bf16x8*>(Krl + ro + ((g4 ^ f7) * 8));
            bf16x8 rB = *reinterpret_cast<const bf16x8*>(Krl + ro + (((4 + g4) ^ f7) * 8));
            sg[nf] = __builtin_amdgcn_mfma_f32_16x16x32_bf16(kA, qf0, z, 0, 0, 0);
            sg[nf] = __builtin_amdgcn_mfma_f32_16x16x32_bf16(kB, qf1, sg[nf], 0, 0, 0);
            sr[nf] = __builtin_amdgcn_mfma_f32_16x16x32_bf16(rA, qr0, z, 0, 0, 0);
            sr[nf] = __builtin_amdgcn_mfma_f32_16x16x32_bf16(rB, qr1, sr[nf], 0, 0, 0);
        }

#pragma unroll
        for (int hh = 0; hh < 2; ++hh) {
#pragma unroll
            for (int j = 0; j < 2; ++j) {
                const int nf = 2 * hh + j;
                float g0 = __expf(sg[nf][0]), g1 = __expf(sg[nf][1]);
                float g2 = __expf(sg[nf][2]), g3 = __expf(sg[nf][3]);
                lgp += (g0 + g1) + (g2 + g3);
                uint2 wg;
                wg.x = cvt_pk_bf16(g0, g1);
                wg.y = cvt_pk_bf16(g2, g3);
                *reinterpret_cast<uint2*>(PgRow + j * 16 + g4 * 4) = wg;
                float r0 = __expf(sr[nf][0]), r1 = __expf(sr[nf][1]);
                float r2 = __expf(sr[nf][2]), r3 = __expf(sr[nf][3]);
                lrp += (r0 + r1) + (r2 + r3);
                uint2 wr;
                wr.x = cvt_pk_bf16(r0, r1);
                wr.y = cvt_pk_bf16(r2, r3);
                *reinterpret_cast<uint2*>(PrRow + j * 16 + g4 * 4) = wr;
            }
            asm volatile("s_waitcnt lgkmcnt(0)" ::: "memory");   // P visible (same wave)
            bf16x8 pg = *reinterpret_cast<const bf16x8*>(PgRow + fk8);
            bf16x8 pr = *reinterpret_cast<const bf16x8*>(PrRow + fk8);
            __builtin_amdgcn_s_setprio(1);
#pragma unroll
            for (int nf2 = 0; nf2 < 4; ++nf2) {
                const int vo = (nf2 * 16 + frow) * 64;
                bf16x8 v = *reinterpret_cast<const bf16x8*>(Vl + vo + (((4 * hh + g4) ^ f7) * 8));
                og[nf2]  = __builtin_amdgcn_mfma_f32_16x16x32_bf16(pg, v, og[nf2], 0, 0, 0);
                orr[nf2] = __builtin_amdgcn_mfma_f32_16x16x32_bf16(pr, v, orr[nf2], 0, 0, 0);
            }
            __builtin_amdgcn_s_setprio(0);
        }

        __syncthreads();
        cur ^= 1;
    }

    lgp += __shfl_xor(lgp, 16); lgp += __shfl_xor(lgp, 32);
    lrp += __shfl_xor(lrp, 16); lrp += __shfl_xor(lrp, 32);
    float ig = 0.45f / lgp, ir = 0.05f / lrp;
    float igr[4], irr[4];
#pragma unroll
    for (int r = 0; r < 4; ++r) {
        igr[r] = __shfl(ig, g4 * 4 + r);
        irr[r] = __shfl(ir, g4 * 4 + r);
    }
#pragma unroll
    for (int nf2 = 0; nf2 < 4; ++nf2) {
#pragma unroll
        for (int r = 0; r < 4; ++r) {
            float val = og[nf2][r] * igr[r] + orr[nf2][r] * irr[r];
            int tq = t0 + g4 * 4 + r;
            attnO[(size_t)(b * NT + tq) * NE + h * 64 + nf2 * 16 + frow] = f2bf(val);
        }
    }
}

// ---------------- launcher ----------------
extern "C" void kernel_launch(void* const* d_in, const int* in_sizes, int n_in,
                              void* d_out, int out_size, void* d_ws, size_t ws_size,
                              hipStream_t stream)
{
    const float* hs  = (const float*)d_in[0];
    const int*   rt  = (const int*)d_in[1];
    const float* Wq  = (const float*)d_in[2];
    const float* bq  = (const float*)d_in[3];
    const float* Wk  = (const float*)d_in[4];
    const float* bk  = (const float*)d_in[5];
    const float* Wv  = (const float*)d_in[6];
    const float* bv  = (const float*)d_in[7];
    const float* Wo  = (const float*)d_in[8];
    const float* bo  = (const float*)d_in[9];
    const float* RWq = (const float*)d_in[10];
    const float* Rbq = (const float*)d_in[11];
    const float* RWk = (const float*)d_in[12];
    const float* Rbk = (const float*)d_in[13];

    unsigned short* w = (unsigned short*)d_ws;
    const size_t NBT = (size_t)BT * NE;   // 8M elems
    const size_t NW  = (size_t)NE * NE;   // 1M elems
    unsigned short* hsB  = w; w += NBT;
    unsigned short* Qb   = w; w += NBT;
    unsigned short* Kb   = w; w += NBT;
    unsigned short* Vb   = w; w += NBT;
    unsigned short* Qrb  = w; w += NBT;
    unsigned short* Krb  = w; w += NBT;
    unsigned short* Vtb  = w; w += NBT;
    unsigned short* atb  = w; w += NBT;
    unsigned short* WqB  = w; w += NW;
    unsigned short* WkB  = w; w += NW;
    unsigned short* WvB  = w; w += NW;
    unsigned short* WoB  = w; w += NW;
    unsigned short* RWqB = w; w += 4 * NW;
    unsigned short* RWkB = w; w += 4 * NW;

    k_cvt7<<<dim3(20480), dim3(256), 0, stream>>>(hs, hsB, Wq, WqB, Wk, WkB, Wv, WvB,
                                                  Wo, WoB, RWq, RWqB, RWk, RWkB);

    GJob jq  = { WqB,  bq,  Qb,  0.125f, 0 };
    GJob jk  = { WkB,  bk,  Kb,  1.0f,   0 };
    GJob jv  = { WvB,  bv,  Vb,  1.0f,   0 };
    GJob jrq = { RWqB, Rbq, Qrb, 0.125f, 1 };
    GJob jrk = { RWkB, Rbk, Krb, 1.0f,   1 };
    k_gemm256<false><<<dim3(640), dim3(512), 0, stream>>>(hsB, jq, jk, jv, jrq, jrk, rt);

    k_vtrans<<<dim3(NB * NH * 16), dim3(256), 0, stream>>>(Vb, Vtb);
    k_attn<<<dim3(NB * NH * 8), dim3(512), 0, stream>>>(Qb, Kb, Qrb, Krb, Vtb, atb);

    // Wo: k_gemmN with 256 blocks = exactly 1 full round of 256 CUs
    GJob jo = { WoB, bo, d_out, 1.0f, 0 };
    k_gemmN<true><<<dim3(256), dim3(512), 0, stream>>>(atb, jo, jo, jo, jo, jo, nullptr);
}